// Round 5
// baseline (2588.044 us; speedup 1.0000x reference)
//
#include <hip/hip_runtime.h>

#define HID 128

typedef __attribute__((ext_vector_type(4))) float floatx4;
typedef __attribute__((ext_vector_type(4))) unsigned short ushort4v;

__device__ __forceinline__ unsigned short f2bf(float f) {
    unsigned u = __builtin_bit_cast(unsigned, f);
    u += 0x7FFF + ((u >> 16) & 1);           // RNE
    return (unsigned short)(u >> 16);
}
__device__ __forceinline__ float bf2f(unsigned short s) {
    unsigned u = ((unsigned)s) << 16;
    return __builtin_bit_cast(float, u);
}

// ---------------- fills ----------------
__global__ void fill0f_kernel(float* __restrict__ p, long n)
{
    long i = (long)blockIdx.x * blockDim.x + threadIdx.x;
    if (i < n) p[i] = 0.f;
}
__global__ void fill0i_kernel(int* __restrict__ p, long n)
{
    long i = (long)blockIdx.x * blockDim.x + threadIdx.x;
    if (i < n) p[i] = 0;
}

// ---------------- diagnostic: constant-encode a value into output (fp32!) ----
__global__ void diag_kernel(float* __restrict__ out, long n, float val)
{
    long i = (long)blockIdx.x * blockDim.x + threadIdx.x;
    if (i < n) out[i] = val;
}

// ---------------- atom encoder: h0 = sum of 9 embedding rows (bf16 out) -------
__global__ __launch_bounds__(128) void encode_kernel(
    const int* __restrict__ x, const float* __restrict__ atom_emb,
    unsigned short* __restrict__ hb, int N)
{
    int n = blockIdx.x;
    if (n >= N) return;
    int c = threadIdx.x;
    __shared__ int xr[9];
    if (c < 9) xr[c] = x[n * 9 + c];
    __syncthreads();
    const int OFF[9] = {0, 119, 123, 135, 147, 157, 163, 169, 171};
    float s = 0.f;
#pragma unroll
    for (int f = 0; f < 9; ++f) s += atom_emb[(xr[f] + OFF[f]) * HID + c];
    hb[(long)n * HID + c] = f2bf(s);
}

// ---------------- bond combo table: 60 x 128 (fp32) ----------------
__global__ __launch_bounds__(128) void combemb_kernel(
    const float* __restrict__ bond_emb, float* __restrict__ comb)
{
    int i = blockIdx.x;
    int c = threadIdx.x;
    int a0 = i / 12, a1 = (i % 12) / 2, a2 = i % 2;
    comb[i * HID + c] = bond_emb[a0 * HID + c] + bond_emb[(5 + a1) * HID + c]
                      + bond_emb[(11 + a2) * HID + c];
}

// ---------------- out-degree (over row = ei[0:E]) ----------------
__global__ void deg_kernel(const int* __restrict__ ei, float* __restrict__ deg, int E)
{
    for (int e = blockIdx.x * blockDim.x + threadIdx.x; e < E; e += gridDim.x * blockDim.x)
        atomicAdd(&deg[ei[e]], 1.f);
}

// deg -> rdeg (1/deg) in place, dis = deg^-0.5
__global__ void fdeg_kernel(float* __restrict__ deg, float* __restrict__ dis, int N)
{
    int n = blockIdx.x * blockDim.x + threadIdx.x;
    if (n < N) {
        float d = deg[n] + 1.f;
        deg[n] = 1.f / d;
        dis[n] = rsqrtf(d);
    }
}

// ---------------- CSR build: in-degree histogram over col = ei[E:2E] ----------
__global__ void ihist_kernel(const int* __restrict__ ei, int* __restrict__ indeg, int E)
{
    for (int e = blockIdx.x * blockDim.x + threadIdx.x; e < E; e += gridDim.x * blockDim.x)
        atomicAdd(&indeg[ei[E + e]], 1);
}

__global__ __launch_bounds__(256) void bsum_kernel(
    const int* __restrict__ indeg, int* __restrict__ partial, int N)
{
    __shared__ int s[256];
    int i = blockIdx.x * 256 + threadIdx.x;
    s[threadIdx.x] = (i < N) ? indeg[i] : 0;
    __syncthreads();
    for (int d = 128; d > 0; d >>= 1) {
        if (threadIdx.x < d) s[threadIdx.x] += s[threadIdx.x + d];
        __syncthreads();
    }
    if (threadIdx.x == 0) partial[blockIdx.x] = s[0];
}

// single block: exclusive scan of block partials (B <= 2048); ptr[N] = total
__global__ __launch_bounds__(256) void scan1_kernel(
    const int* __restrict__ partial, int* __restrict__ offs,
    int* __restrict__ ptr, int B, int N)
{
    __shared__ int s[256];
    __shared__ int carry_s;
    int tid = threadIdx.x;
    if (tid == 0) carry_s = 0;
    __syncthreads();
    for (int base = 0; base < B; base += 256) {
        int i = base + tid;
        int v = (i < B) ? partial[i] : 0;
        s[tid] = v;
        __syncthreads();
        for (int d = 1; d < 256; d <<= 1) {
            int t = (tid >= d) ? s[tid - d] : 0;
            __syncthreads();
            s[tid] += t;
            __syncthreads();
        }
        int carry = carry_s;
        if (i < B) offs[i] = carry + s[tid] - v;
        __syncthreads();
        if (tid == 0) carry_s = carry + s[255];
        __syncthreads();
    }
    if (tid == 0) ptr[N] = carry_s;
}

// per-block exclusive scan + block offset -> ptr; also init cursor
__global__ __launch_bounds__(256) void scan2_kernel(
    const int* __restrict__ indeg, const int* __restrict__ offs,
    int* __restrict__ ptr, int* __restrict__ cursor, int N)
{
    __shared__ int s[256];
    int tid = threadIdx.x;
    int i = blockIdx.x * 256 + tid;
    int v = (i < N) ? indeg[i] : 0;
    s[tid] = v;
    __syncthreads();
    for (int d = 1; d < 256; d <<= 1) {
        int t = (tid >= d) ? s[tid - d] : 0;
        __syncthreads();
        s[tid] += t;
        __syncthreads();
    }
    if (i < N) {
        int ex = offs[blockIdx.x] + s[tid] - v;
        ptr[i] = ex;
        cursor[i] = ex;
    }
}

__global__ void fillcsr_kernel(const int* __restrict__ ei, int* __restrict__ cursor,
                               int* __restrict__ perm, int E)
{
    for (int e = blockIdx.x * blockDim.x + threadIdx.x; e < E; e += gridDim.x * blockDim.x) {
        int col = ei[E + e];
        int pos = atomicAdd(&cursor[col], 1);
        perm[pos] = e;
    }
}

// ---------------- z = h @ W^T + b  (pure fp32 VALU, no MFMA) ----------------
// block = 128 threads; thread c owns output col c and W row c in 128 VGPRs.
// h rows broadcast through LDS, GN nodes per stage.
#define GN 4
__global__ __launch_bounds__(128) void gemm_kernel(
    const unsigned short* __restrict__ hb, const float* __restrict__ W,
    const float* __restrict__ bias, unsigned short* __restrict__ zb, int N)
{
    int c = threadIdx.x;
    float Wr[HID];
#pragma unroll
    for (int k4 = 0; k4 < HID / 4; ++k4) {
        floatx4 w = *reinterpret_cast<const floatx4*>(W + (long)c * HID + k4 * 4);
        Wr[4 * k4 + 0] = w[0]; Wr[4 * k4 + 1] = w[1];
        Wr[4 * k4 + 2] = w[2]; Wr[4 * k4 + 3] = w[3];
    }
    float bc = bias[c];
    __shared__ float hs[GN][HID];
    long stride = (long)gridDim.x * GN;
    for (long n0 = (long)blockIdx.x * GN; n0 < N; n0 += stride) {
        __syncthreads();   // protect hs from previous round's readers
#pragma unroll
        for (int g = 0; g < GN; ++g) {
            long n = n0 + g;
            unsigned short v = (n < N) ? hb[n * HID + c] : (unsigned short)0;
            hs[g][c] = bf2f(v);
        }
        __syncthreads();
#pragma unroll
        for (int g = 0; g < GN; ++g) {
            long n = n0 + g;
            if (n < N) {
                float acc = bc;
#pragma unroll
                for (int k4 = 0; k4 < HID / 4; ++k4) {
                    floatx4 hv = *reinterpret_cast<const floatx4*>(&hs[g][k4 * 4]);
                    acc += hv[0] * Wr[4 * k4 + 0] + hv[1] * Wr[4 * k4 + 1]
                         + hv[2] * Wr[4 * k4 + 2] + hv[3] * Wr[4 * k4 + 3];
                }
                zb[n * HID + c] = f2bf(acc);
            }
        }
    }
}

// ---------------- fused: self-term + CSR gather + relu + BN + combine -------
// 32 lanes per node, lane owns 4 cols. No atomics, no agg buffer.
__global__ __launch_bounds__(256) void agg_kernel(
    const int* __restrict__ ei, const int* __restrict__ attr,
    const int* __restrict__ ptr, const int* __restrict__ perm,
    const float* __restrict__ comb, const float* __restrict__ dis,
    const float* __restrict__ rdeg, const float* __restrict__ root,
    const float* __restrict__ gamma, const float* __restrict__ beta,
    const float* __restrict__ mean, const float* __restrict__ var,
    const unsigned short* __restrict__ zb, unsigned short* __restrict__ hb,
    float fi, int N, int E)
{
    int n = blockIdx.x * 8 + (threadIdx.x >> 5);
    if (n >= N) return;
    int c = (threadIdx.x & 31) * 4;

    ushort4v zv = *reinterpret_cast<const ushort4v*>(zb + (long)n * HID + c);
    floatx4 rt = *reinterpret_cast<const floatx4*>(root + c);
    float rd = rdeg[n], di = dis[n];
    floatx4 acc;
#pragma unroll
    for (int j = 0; j < 4; ++j) acc[j] = fmaxf(bf2f(zv[j]) + rt[j], 0.f) * rd;

    int jb = ptr[n], je = ptr[n + 1];
    for (int j2 = jb; j2 < je; ++j2) {
        int e = perm[j2];
        int r = ei[e];
        float nrm = dis[r] * di;
        int ci = attr[e * 3] * 12 + attr[e * 3 + 1] * 2 + attr[e * 3 + 2];
        floatx4 ev = *reinterpret_cast<const floatx4*>(comb + ci * HID + c);
        ushort4v zr = *reinterpret_cast<const ushort4v*>(zb + (long)r * HID + c);
#pragma unroll
        for (int j = 0; j < 4; ++j) acc[j] += fmaxf(bf2f(zr[j]) + ev[j], 0.f) * nrm;
    }

    floatx4 gm = *reinterpret_cast<const floatx4*>(gamma + c);
    floatx4 bt = *reinterpret_cast<const floatx4*>(beta + c);
    floatx4 mn = *reinterpret_cast<const floatx4*>(mean + c);
    floatx4 vr = *reinterpret_cast<const floatx4*>(var + c);
    unsigned short* hp = hb + (long)n * HID + c;
    ushort4v hv = *reinterpret_cast<const ushort4v*>(hp);
    ushort4v o;
#pragma unroll
    for (int j = 0; j < 4; ++j) {
        float t = fmaxf(acc[j], 0.f);
        t = (t - mn[j]) * (gm[j] * rsqrtf(vr[j] + 1e-5f)) + bt[j];
        float hn = fi * bf2f(hv[j]) + (1.f - fi) * t;
        o[j] = f2bf(hn);
    }
    *reinterpret_cast<ushort4v*>(hp) = o;
}

// ---------------- pooling (atomics; once at end) ----------------
__global__ __launch_bounds__(256) void pool_kernel(
    const unsigned short* __restrict__ hb, const int* __restrict__ batch,
    float* __restrict__ pooled, float* __restrict__ counts, long NV)
{
    long idx = (long)blockIdx.x * blockDim.x + threadIdx.x;
    if (idx >= NV) return;
    long n = idx >> 5;
    int c = (int)(idx & 31) * 4;
    int b = batch[n];
    ushort4v hv = *reinterpret_cast<const ushort4v*>(hb + n * HID + c);
    float* pp = pooled + (long)b * HID + c;
#pragma unroll
    for (int j = 0; j < 4; ++j) atomicAdd(pp + j, bf2f(hv[j]));
    if ((idx & 31) == 0) atomicAdd(&counts[b], 1.f);
}

// ---------------- final linear (fp32 out — reference output dtype!) ---------
__global__ __launch_bounds__(128) void lin_kernel(
    const float* __restrict__ pooled, const float* __restrict__ counts,
    const float* __restrict__ lin_W, const float* __restrict__ lin_b,
    float* __restrict__ out, int G)
{
    int g = blockIdx.x;
    if (g >= G) return;
    int t = threadIdx.x;
    __shared__ float p[HID];
    float cnt = fmaxf(counts[g], 1.f);
    p[t] = pooled[(long)g * HID + t] / cnt;
    __syncthreads();
    float acc = lin_b[t];
#pragma unroll 8
    for (int k = 0; k < HID; ++k) acc += p[k] * lin_W[t * HID + k];
    out[(long)g * HID + t] = acc;
}

extern "C" void kernel_launch(void* const* d_in, const int* in_sizes, int n_in,
                              void* d_out, int out_size, void* d_ws, size_t ws_size,
                              hipStream_t stream)
{
    const int* x          = (const int*)d_in[0];
    const int* ei         = (const int*)d_in[1];
    const int* attr       = (const int*)d_in[2];
    const int* batch      = (const int*)d_in[3];
    const float* atom_emb = (const float*)d_in[4];
    const float* bond_emb = (const float*)d_in[5];
    const float* conv_W   = (const float*)d_in[6];
    const float* conv_b   = (const float*)d_in[7];
    const float* root     = (const float*)d_in[8];
    const float* gamma    = (const float*)d_in[9];
    const float* beta     = (const float*)d_in[10];
    const float* mean     = (const float*)d_in[11];
    const float* var      = (const float*)d_in[12];
    const float* lin_W    = (const float*)d_in[13];
    const float* lin_b    = (const float*)d_in[14];
    float* out = (float*)d_out;             // fp32 output (reference returns float32)

    const int N = in_sizes[0] / 9;
    const int E = in_sizes[1] / 2;
    const int G = out_size / HID;
    const int B = (N + 255) / 256;          // scan blocks

    auto al = [](size_t b) { return (b + 255) & ~(size_t)255; };
    const size_t need =
        al((size_t)N * HID * 2) +     // hb
        al((size_t)N * HID * 2) +     // zb
        al((size_t)(N + 1) * 4) +     // ptr
        al((size_t)N * 4) +           // cursor
        al((size_t)E * 4) +           // perm
        al((size_t)N * 4) +           // indeg
        al((size_t)2048 * 4) * 2 +    // partial + offs
        al((size_t)N * 4) * 2 +       // rdeg + dis
        al((size_t)G * HID * 4) +     // pooled
        al((size_t)G * 4) +           // counts
        al((size_t)60 * HID * 4);     // comb

    if (ws_size < need || B > 2048) {
        float v = (B > 2048) ? 3000.f : (1000.f + (float)(ws_size >> 20));
        long n = (long)out_size;
        diag_kernel<<<(int)((n + 255) / 256), 256, 0, stream>>>(out, n, v);
        return;
    }

    char* wsp = (char*)d_ws;
    size_t used = 0;
    auto alloc = [&](size_t bytes) { char* p = wsp + used; used += al(bytes); return p; };
    unsigned short* hb = (unsigned short*)alloc((size_t)N * HID * 2);
    unsigned short* zb = (unsigned short*)alloc((size_t)N * HID * 2);
    int* ptr     = (int*)alloc((size_t)(N + 1) * 4);
    int* cursor  = (int*)alloc((size_t)N * 4);
    int* perm    = (int*)alloc((size_t)E * 4);
    int* indeg   = (int*)alloc((size_t)N * 4);
    int* partial = (int*)alloc((size_t)2048 * 4);
    int* offs    = (int*)alloc((size_t)2048 * 4);
    float* rdeg  = (float*)alloc((size_t)N * 4);
    float* dis   = (float*)alloc((size_t)N * 4);
    float* pooled= (float*)alloc((size_t)G * HID * 4);
    float* counts= (float*)alloc((size_t)G * 4);
    float* comb  = (float*)alloc((size_t)60 * HID * 4);

    // ---- prologue ----
    fill0f_kernel<<<(N + 255) / 256, 256, 0, stream>>>(rdeg, N);
    fill0i_kernel<<<(N + 255) / 256, 256, 0, stream>>>(indeg, N);
    fill0f_kernel<<<(int)(((long)G * HID + 255) / 256), 256, 0, stream>>>(pooled, (long)G * HID);
    fill0f_kernel<<<(G + 255) / 256, 256, 0, stream>>>(counts, G);
    combemb_kernel<<<60, 128, 0, stream>>>(bond_emb, comb);
    encode_kernel<<<N, 128, 0, stream>>>(x, atom_emb, hb, N);
    deg_kernel<<<1024, 256, 0, stream>>>(ei, rdeg, E);
    fdeg_kernel<<<(N + 255) / 256, 256, 0, stream>>>(rdeg, dis, N);
    // CSR build (in-edges grouped by destination col)
    ihist_kernel<<<1024, 256, 0, stream>>>(ei, indeg, E);
    bsum_kernel<<<B, 256, 0, stream>>>(indeg, partial, N);
    scan1_kernel<<<1, 256, 0, stream>>>(partial, offs, ptr, B, N);
    scan2_kernel<<<B, 256, 0, stream>>>(indeg, offs, ptr, cursor, N);
    fillcsr_kernel<<<1024, 256, 0, stream>>>(ei, cursor, perm, E);

    // ---- loop (i=1 is identity: h = 1*old + 0*z, skipped) ----
    const float fis[4] = {0.f, 2.f, 3.f, 4.f};
    for (int t = 0; t < 4; ++t) {
        gemm_kernel<<<2048, 128, 0, stream>>>(hb, conv_W, conv_b, zb, N);
        agg_kernel<<<(N + 7) / 8, 256, 0, stream>>>(ei, attr, ptr, perm, comb, dis, rdeg,
                                                    root, gamma, beta, mean, var,
                                                    zb, hb, fis[t], N, E);
    }

    // ---- pooling + output linear ----
    pool_kernel<<<(int)(((long)N * 32 + 255) / 256), 256, 0, stream>>>(hb, batch, pooled, counts, (long)N * 32);
    lin_kernel<<<G, 128, 0, stream>>>(pooled, counts, lin_W, lin_b, out, G);
}

// Round 6
// 1115.990 us; speedup vs baseline: 2.3191x; 2.3191x over previous
//
#include <hip/hip_runtime.h>

#define HID 128

typedef __attribute__((ext_vector_type(8))) short short8;
typedef __attribute__((ext_vector_type(4))) float floatx4;
typedef __attribute__((ext_vector_type(4))) unsigned short ushort4v;

__device__ __forceinline__ unsigned short f2bf(float f) {
    unsigned u = __builtin_bit_cast(unsigned, f);
    u += 0x7FFF + ((u >> 16) & 1);           // RNE
    return (unsigned short)(u >> 16);
}
__device__ __forceinline__ float bf2f(unsigned short s) {
    unsigned u = ((unsigned)s) << 16;
    return __builtin_bit_cast(float, u);
}

// ---------------- fills ----------------
__global__ void fill0f_kernel(float* __restrict__ p, long n)
{
    long i = (long)blockIdx.x * blockDim.x + threadIdx.x;
    if (i < n) p[i] = 0.f;
}
__global__ void fill0i_kernel(int* __restrict__ p, long n)
{
    long i = (long)blockIdx.x * blockDim.x + threadIdx.x;
    if (i < n) p[i] = 0;
}

// ---------------- diagnostic ----------------
__global__ void diag_kernel(float* __restrict__ out, long n, float val)
{
    long i = (long)blockIdx.x * blockDim.x + threadIdx.x;
    if (i < n) out[i] = val;
}

// ---------------- atom encoder: h0 = sum of 9 embedding rows (bf16 out) -------
__global__ __launch_bounds__(128) void encode_kernel(
    const int* __restrict__ x, const float* __restrict__ atom_emb,
    unsigned short* __restrict__ hb, int N)
{
    int n = blockIdx.x;
    if (n >= N) return;
    int c = threadIdx.x;
    __shared__ int xr[9];
    if (c < 9) xr[c] = x[n * 9 + c];
    __syncthreads();
    const int OFF[9] = {0, 119, 123, 135, 147, 157, 163, 169, 171};
    float s = 0.f;
#pragma unroll
    for (int f = 0; f < 9; ++f) s += atom_emb[(xr[f] + OFF[f]) * HID + c];
    hb[(long)n * HID + c] = f2bf(s);
}

// ---------------- conv_W -> bf16 ----------------
__global__ void cvtW_kernel(const float* __restrict__ W, unsigned short* __restrict__ Wb)
{
    int i = blockIdx.x * 256 + threadIdx.x;
    if (i < HID * HID) Wb[i] = f2bf(W[i]);
}

// ---------------- bond combo table: 60 x 128 (fp32) ----------------
__global__ __launch_bounds__(128) void combemb_kernel(
    const float* __restrict__ bond_emb, float* __restrict__ comb)
{
    int i = blockIdx.x;
    int c = threadIdx.x;
    int a0 = i / 12, a1 = (i % 12) / 2, a2 = i % 2;
    comb[i * HID + c] = bond_emb[a0 * HID + c] + bond_emb[(5 + a1) * HID + c]
                      + bond_emb[(11 + a2) * HID + c];
}

// ---------------- out-degree (over row = ei[0:E]) ----------------
__global__ void deg_kernel(const int* __restrict__ ei, float* __restrict__ deg, int E)
{
    for (int e = blockIdx.x * blockDim.x + threadIdx.x; e < E; e += gridDim.x * blockDim.x)
        atomicAdd(&deg[ei[e]], 1.f);
}

// deg -> rdeg (1/deg) in place, dis = deg^-0.5
__global__ void fdeg_kernel(float* __restrict__ deg, float* __restrict__ dis, int N)
{
    int n = blockIdx.x * blockDim.x + threadIdx.x;
    if (n < N) {
        float d = deg[n] + 1.f;
        deg[n] = 1.f / d;
        dis[n] = rsqrtf(d);
    }
}

// ---------------- CSR build ----------------
__global__ void ihist_kernel(const int* __restrict__ ei, int* __restrict__ indeg, int E)
{
    for (int e = blockIdx.x * blockDim.x + threadIdx.x; e < E; e += gridDim.x * blockDim.x)
        atomicAdd(&indeg[ei[E + e]], 1);
}

__global__ __launch_bounds__(256) void bsum_kernel(
    const int* __restrict__ indeg, int* __restrict__ partial, int N)
{
    __shared__ int s[256];
    int i = blockIdx.x * 256 + threadIdx.x;
    s[threadIdx.x] = (i < N) ? indeg[i] : 0;
    __syncthreads();
    for (int d = 128; d > 0; d >>= 1) {
        if (threadIdx.x < d) s[threadIdx.x] += s[threadIdx.x + d];
        __syncthreads();
    }
    if (threadIdx.x == 0) partial[blockIdx.x] = s[0];
}

__global__ __launch_bounds__(256) void scan1_kernel(
    const int* __restrict__ partial, int* __restrict__ offs,
    int* __restrict__ ptr, int B, int N)
{
    __shared__ int s[256];
    __shared__ int carry_s;
    int tid = threadIdx.x;
    if (tid == 0) carry_s = 0;
    __syncthreads();
    for (int base = 0; base < B; base += 256) {
        int i = base + tid;
        int v = (i < B) ? partial[i] : 0;
        s[tid] = v;
        __syncthreads();
        for (int d = 1; d < 256; d <<= 1) {
            int t = (tid >= d) ? s[tid - d] : 0;
            __syncthreads();
            s[tid] += t;
            __syncthreads();
        }
        int carry = carry_s;
        if (i < B) offs[i] = carry + s[tid] - v;
        __syncthreads();
        if (tid == 0) carry_s = carry + s[255];
        __syncthreads();
    }
    if (tid == 0) ptr[N] = carry_s;
}

__global__ __launch_bounds__(256) void scan2_kernel(
    const int* __restrict__ indeg, const int* __restrict__ offs,
    int* __restrict__ ptr, int* __restrict__ cursor, int N)
{
    __shared__ int s[256];
    int tid = threadIdx.x;
    int i = blockIdx.x * 256 + tid;
    int v = (i < N) ? indeg[i] : 0;
    s[tid] = v;
    __syncthreads();
    for (int d = 1; d < 256; d <<= 1) {
        int t = (tid >= d) ? s[tid - d] : 0;
        __syncthreads();
        s[tid] += t;
        __syncthreads();
    }
    if (i < N) {
        int ex = offs[blockIdx.x] + s[tid] - v;
        ptr[i] = ex;
        cursor[i] = ex;
    }
}

__global__ void fillcsr_kernel(const int* __restrict__ ei, int* __restrict__ cursor,
                               int* __restrict__ perm, int E)
{
    for (int e = blockIdx.x * blockDim.x + threadIdx.x; e < E; e += gridDim.x * blockDim.x) {
        int col = ei[E + e];
        int pos = atomicAdd(&cursor[col], 1);
        perm[pos] = e;
    }
}

// ---------------- z = h @ W^T + b  (bf16 MFMA, bf16 in/out, no LDS) ----------
// Layout verified: rounds 3/4 produced bit-identical results (MFMA vs fp32 VALU).
__global__ __launch_bounds__(256) void gemm_kernel(
    const unsigned short* __restrict__ hb, const unsigned short* __restrict__ Wb,
    const float* __restrict__ bias, unsigned short* __restrict__ zb, int N)
{
    int wave = threadIdx.x >> 6;
    int lane = threadIdx.x & 63;
    int l15 = lane & 15;
    int q = lane >> 4;
    long row0 = (long)blockIdx.x * 128 + wave * 32;

    short8 a[2][4];
#pragma unroll
    for (int mt = 0; mt < 2; ++mt) {
        long rl = row0 + mt * 16 + l15;
        if (rl > (long)N - 1) rl = (long)N - 1;   // clamp tail (stores guarded below)
        const unsigned short* ap = hb + rl * HID + q * 8;
#pragma unroll
        for (int kb = 0; kb < 4; ++kb)
            a[mt][kb] = *reinterpret_cast<const short8*>(ap + kb * 32);
    }

    floatx4 acc[2][8];
#pragma unroll
    for (int mt = 0; mt < 2; ++mt)
#pragma unroll
        for (int nt = 0; nt < 8; ++nt) {
            floatx4 zz = {0.f, 0.f, 0.f, 0.f};
            acc[mt][nt] = zz;
        }

#pragma unroll
    for (int nt = 0; nt < 8; ++nt) {
        const unsigned short* bp = Wb + (nt * 16 + l15) * HID + q * 8;
#pragma unroll
        for (int kb = 0; kb < 4; ++kb) {
            short8 b = *reinterpret_cast<const short8*>(bp + kb * 32);
            acc[0][nt] = __builtin_amdgcn_mfma_f32_16x16x32_bf16(a[0][kb], b, acc[0][nt], 0, 0, 0);
            acc[1][nt] = __builtin_amdgcn_mfma_f32_16x16x32_bf16(a[1][kb], b, acc[1][nt], 0, 0, 0);
        }
    }

    float bi[8];
#pragma unroll
    for (int nt = 0; nt < 8; ++nt) bi[nt] = bias[nt * 16 + l15];

    // C/D layout (m89/m91): row = q*4 + reg, col = l15 + 16*nt
#pragma unroll
    for (int mt = 0; mt < 2; ++mt) {
#pragma unroll
        for (int r = 0; r < 4; ++r) {
            long rr = row0 + mt * 16 + q * 4 + r;
            if (rr < N) {
                unsigned short* zp = zb + rr * HID + l15;
#pragma unroll
                for (int nt = 0; nt < 8; ++nt)
                    zp[nt * 16] = f2bf(acc[mt][nt][r] + bi[nt]);
            }
        }
    }
}

// ---------------- fused: self-term + CSR gather + relu + BN + combine -------
__global__ __launch_bounds__(256) void agg_kernel(
    const int* __restrict__ ei, const int* __restrict__ attr,
    const int* __restrict__ ptr, const int* __restrict__ perm,
    const float* __restrict__ comb, const float* __restrict__ dis,
    const float* __restrict__ rdeg, const float* __restrict__ root,
    const float* __restrict__ gamma, const float* __restrict__ beta,
    const float* __restrict__ mean, const float* __restrict__ var,
    const unsigned short* __restrict__ zb, unsigned short* __restrict__ hb,
    float fi, int N, int E)
{
    int n = blockIdx.x * 8 + (threadIdx.x >> 5);
    if (n >= N) return;
    int c = (threadIdx.x & 31) * 4;

    ushort4v zv = *reinterpret_cast<const ushort4v*>(zb + (long)n * HID + c);
    floatx4 rt = *reinterpret_cast<const floatx4*>(root + c);
    float rd = rdeg[n], di = dis[n];
    floatx4 acc;
#pragma unroll
    for (int j = 0; j < 4; ++j) acc[j] = fmaxf(bf2f(zv[j]) + rt[j], 0.f) * rd;

    int jb = ptr[n], je = ptr[n + 1];
    for (int j2 = jb; j2 < je; ++j2) {
        int e = perm[j2];
        int r = ei[e];
        float nrm = dis[r] * di;
        int ci = attr[e * 3] * 12 + attr[e * 3 + 1] * 2 + attr[e * 3 + 2];
        floatx4 ev = *reinterpret_cast<const floatx4*>(comb + ci * HID + c);
        ushort4v zr = *reinterpret_cast<const ushort4v*>(zb + (long)r * HID + c);
#pragma unroll
        for (int j = 0; j < 4; ++j) acc[j] += fmaxf(bf2f(zr[j]) + ev[j], 0.f) * nrm;
    }

    floatx4 gm = *reinterpret_cast<const floatx4*>(gamma + c);
    floatx4 bt = *reinterpret_cast<const floatx4*>(beta + c);
    floatx4 mn = *reinterpret_cast<const floatx4*>(mean + c);
    floatx4 vr = *reinterpret_cast<const floatx4*>(var + c);
    unsigned short* hp = hb + (long)n * HID + c;
    ushort4v hv = *reinterpret_cast<const ushort4v*>(hp);
    ushort4v o;
#pragma unroll
    for (int j = 0; j < 4; ++j) {
        float t = fmaxf(acc[j], 0.f);
        t = (t - mn[j]) * (gm[j] * rsqrtf(vr[j] + 1e-5f)) + bt[j];
        float hn = fi * bf2f(hv[j]) + (1.f - fi) * t;
        o[j] = f2bf(hn);
    }
    *reinterpret_cast<ushort4v*>(hp) = o;
}

// ---------------- fused mean-pool + final linear (batch sorted -> no atomics) --
__device__ __forceinline__ int lbound(const int* __restrict__ a, int n, int v)
{
    int lo = 0, hi = n;
    while (lo < hi) {
        int mid = (lo + hi) >> 1;
        if (a[mid] < v) lo = mid + 1; else hi = mid;
    }
    return lo;
}

__global__ __launch_bounds__(128) void poollin_kernel(
    const unsigned short* __restrict__ hb, const int* __restrict__ batch,
    const float* __restrict__ lin_W, const float* __restrict__ lin_b,
    float* __restrict__ out, int N, int G)
{
    int g = blockIdx.x;
    if (g >= G) return;
    int t = threadIdx.x;
    // wave-uniform binary search (same result in every thread; L1-broadcast reads)
    int lo = lbound(batch, N, g);
    int hi = lbound(batch, N, g + 1);
    float sum = 0.f;
    for (int n = lo; n < hi; ++n) sum += bf2f(hb[(long)n * HID + t]);
    float cnt = (hi > lo) ? (float)(hi - lo) : 1.f;
    __shared__ float p[HID];
    p[t] = sum / cnt;
    __syncthreads();
    float acc = lin_b[t];
#pragma unroll 8
    for (int k = 0; k < HID; ++k) acc += p[k] * lin_W[t * HID + k];
    out[(long)g * HID + t] = acc;
}

extern "C" void kernel_launch(void* const* d_in, const int* in_sizes, int n_in,
                              void* d_out, int out_size, void* d_ws, size_t ws_size,
                              hipStream_t stream)
{
    const int* x          = (const int*)d_in[0];
    const int* ei         = (const int*)d_in[1];
    const int* attr       = (const int*)d_in[2];
    const int* batch      = (const int*)d_in[3];
    const float* atom_emb = (const float*)d_in[4];
    const float* bond_emb = (const float*)d_in[5];
    const float* conv_W   = (const float*)d_in[6];
    const float* conv_b   = (const float*)d_in[7];
    const float* root     = (const float*)d_in[8];
    const float* gamma    = (const float*)d_in[9];
    const float* beta     = (const float*)d_in[10];
    const float* mean     = (const float*)d_in[11];
    const float* var      = (const float*)d_in[12];
    const float* lin_W    = (const float*)d_in[13];
    const float* lin_b    = (const float*)d_in[14];
    float* out = (float*)d_out;             // fp32 output

    const int N = in_sizes[0] / 9;
    const int E = in_sizes[1] / 2;
    const int G = out_size / HID;
    const int B = (N + 255) / 256;

    auto al = [](size_t b) { return (b + 255) & ~(size_t)255; };
    const size_t need =
        al((size_t)N * HID * 2) +     // hb
        al((size_t)N * HID * 2) +     // zb
        al((size_t)(N + 1) * 4) +     // ptr
        al((size_t)N * 4) +           // cursor
        al((size_t)E * 4) +           // perm
        al((size_t)N * 4) +           // indeg
        al((size_t)2048 * 4) * 2 +    // partial + offs
        al((size_t)N * 4) * 2 +       // rdeg + dis
        al((size_t)60 * HID * 4) +    // comb
        al((size_t)HID * HID * 2);    // Wb

    if (ws_size < need || B > 2048) {
        float v = (B > 2048) ? 3000.f : (1000.f + (float)(ws_size >> 20));
        long n = (long)out_size;
        diag_kernel<<<(int)((n + 255) / 256), 256, 0, stream>>>(out, n, v);
        return;
    }

    char* wsp = (char*)d_ws;
    size_t used = 0;
    auto alloc = [&](size_t bytes) { char* p = wsp + used; used += al(bytes); return p; };
    unsigned short* hb = (unsigned short*)alloc((size_t)N * HID * 2);
    unsigned short* zb = (unsigned short*)alloc((size_t)N * HID * 2);
    int* ptr     = (int*)alloc((size_t)(N + 1) * 4);
    int* cursor  = (int*)alloc((size_t)N * 4);
    int* perm    = (int*)alloc((size_t)E * 4);
    int* indeg   = (int*)alloc((size_t)N * 4);
    int* partial = (int*)alloc((size_t)2048 * 4);
    int* offs    = (int*)alloc((size_t)2048 * 4);
    float* rdeg  = (float*)alloc((size_t)N * 4);
    float* dis   = (float*)alloc((size_t)N * 4);
    float* comb  = (float*)alloc((size_t)60 * HID * 4);
    unsigned short* Wb = (unsigned short*)alloc((size_t)HID * HID * 2);

    // ---- prologue ----
    fill0f_kernel<<<(N + 255) / 256, 256, 0, stream>>>(rdeg, N);
    fill0i_kernel<<<(N + 255) / 256, 256, 0, stream>>>(indeg, N);
    cvtW_kernel<<<(HID * HID + 255) / 256, 256, 0, stream>>>(conv_W, Wb);
    combemb_kernel<<<60, 128, 0, stream>>>(bond_emb, comb);
    encode_kernel<<<N, 128, 0, stream>>>(x, atom_emb, hb, N);
    deg_kernel<<<1024, 256, 0, stream>>>(ei, rdeg, E);
    fdeg_kernel<<<(N + 255) / 256, 256, 0, stream>>>(rdeg, dis, N);
    ihist_kernel<<<1024, 256, 0, stream>>>(ei, indeg, E);
    bsum_kernel<<<B, 256, 0, stream>>>(indeg, partial, N);
    scan1_kernel<<<1, 256, 0, stream>>>(partial, offs, ptr, B, N);
    scan2_kernel<<<B, 256, 0, stream>>>(indeg, offs, ptr, cursor, N);
    fillcsr_kernel<<<1024, 256, 0, stream>>>(ei, cursor, perm, E);

    // ---- loop (i=1 is identity: h = 1*old + 0*z, skipped) ----
    const float fis[4] = {0.f, 2.f, 3.f, 4.f};
    const int gemm_blocks = (N + 127) / 128;
    for (int t = 0; t < 4; ++t) {
        gemm_kernel<<<gemm_blocks, 256, 0, stream>>>(hb, Wb, conv_b, zb, N);
        agg_kernel<<<(N + 7) / 8, 256, 0, stream>>>(ei, attr, ptr, perm, comb, dis, rdeg,
                                                    root, gamma, beta, mean, var,
                                                    zb, hb, fis[t], N, E);
    }

    // ---- fused mean-pool + output linear (no atomics) ----
    poollin_kernel<<<G, 128, 0, stream>>>(hb, batch, lin_W, lin_b, out, N, G);
}

// Round 7
// 971.019 us; speedup vs baseline: 2.6653x; 1.1493x over previous
//
#include <hip/hip_runtime.h>

#define HID 128

typedef __attribute__((ext_vector_type(8))) short short8;
typedef __attribute__((ext_vector_type(8))) unsigned short ushort8v;
typedef __attribute__((ext_vector_type(4))) float floatx4;
typedef __attribute__((ext_vector_type(4))) unsigned short ushort4v;

__device__ __forceinline__ unsigned short f2bf(float f) {
    unsigned u = __builtin_bit_cast(unsigned, f);
    u += 0x7FFF + ((u >> 16) & 1);           // RNE
    return (unsigned short)(u >> 16);
}
__device__ __forceinline__ float bf2f(unsigned short s) {
    unsigned u = ((unsigned)s) << 16;
    return __builtin_bit_cast(float, u);
}

// ---------------- fills ----------------
__global__ void fill0f_kernel(float* __restrict__ p, long n)
{
    long i = (long)blockIdx.x * blockDim.x + threadIdx.x;
    if (i < n) p[i] = 0.f;
}
__global__ void fill0i_kernel(int* __restrict__ p, long n)
{
    long i = (long)blockIdx.x * blockDim.x + threadIdx.x;
    if (i < n) p[i] = 0;
}

// ---------------- diagnostic ----------------
__global__ void diag_kernel(float* __restrict__ out, long n, float val)
{
    long i = (long)blockIdx.x * blockDim.x + threadIdx.x;
    if (i < n) out[i] = val;
}

// ---------------- atom encoder ----------------
__global__ __launch_bounds__(128) void encode_kernel(
    const int* __restrict__ x, const float* __restrict__ atom_emb,
    unsigned short* __restrict__ hb, int N)
{
    int n = blockIdx.x;
    if (n >= N) return;
    int c = threadIdx.x;
    __shared__ int xr[9];
    if (c < 9) xr[c] = x[n * 9 + c];
    __syncthreads();
    const int OFF[9] = {0, 119, 123, 135, 147, 157, 163, 169, 171};
    float s = 0.f;
#pragma unroll
    for (int f = 0; f < 9; ++f) s += atom_emb[(xr[f] + OFF[f]) * HID + c];
    hb[(long)n * HID + c] = f2bf(s);
}

// ---------------- conv_W -> bf16 ----------------
__global__ void cvtW_kernel(const float* __restrict__ W, unsigned short* __restrict__ Wb)
{
    int i = blockIdx.x * 256 + threadIdx.x;
    if (i < HID * HID) Wb[i] = f2bf(W[i]);
}

// ---------------- bond combo table: 60 x 128 (fp32) ----------------
__global__ __launch_bounds__(128) void combemb_kernel(
    const float* __restrict__ bond_emb, float* __restrict__ comb)
{
    int i = blockIdx.x;
    int c = threadIdx.x;
    int a0 = i / 12, a1 = (i % 12) / 2, a2 = i % 2;
    comb[i * HID + c] = bond_emb[a0 * HID + c] + bond_emb[(5 + a1) * HID + c]
                      + bond_emb[(11 + a2) * HID + c];
}

// ---------------- merged: out-degree (row) + in-degree histogram (col) -------
__global__ void hist_kernel(const int* __restrict__ ei, float* __restrict__ deg,
                            int* __restrict__ indeg, int E)
{
    for (int e = blockIdx.x * blockDim.x + threadIdx.x; e < E; e += gridDim.x * blockDim.x) {
        atomicAdd(&deg[ei[e]], 1.f);
        atomicAdd(&indeg[ei[E + e]], 1);
    }
}

// deg -> rdeg (1/deg) in place, dis = deg^-0.5
__global__ void fdeg_kernel(float* __restrict__ deg, float* __restrict__ dis, int N)
{
    int n = blockIdx.x * blockDim.x + threadIdx.x;
    if (n < N) {
        float d = deg[n] + 1.f;
        deg[n] = 1.f / d;
        dis[n] = rsqrtf(d);
    }
}

// ---------------- CSR scan chain ----------------
__global__ __launch_bounds__(256) void bsum_kernel(
    const int* __restrict__ indeg, int* __restrict__ partial, int N)
{
    __shared__ int s[256];
    int i = blockIdx.x * 256 + threadIdx.x;
    s[threadIdx.x] = (i < N) ? indeg[i] : 0;
    __syncthreads();
    for (int d = 128; d > 0; d >>= 1) {
        if (threadIdx.x < d) s[threadIdx.x] += s[threadIdx.x + d];
        __syncthreads();
    }
    if (threadIdx.x == 0) partial[blockIdx.x] = s[0];
}

__global__ __launch_bounds__(256) void scan1_kernel(
    const int* __restrict__ partial, int* __restrict__ offs,
    int* __restrict__ ptr, int B, int N)
{
    __shared__ int s[256];
    __shared__ int carry_s;
    int tid = threadIdx.x;
    if (tid == 0) carry_s = 0;
    __syncthreads();
    for (int base = 0; base < B; base += 256) {
        int i = base + tid;
        int v = (i < B) ? partial[i] : 0;
        s[tid] = v;
        __syncthreads();
        for (int d = 1; d < 256; d <<= 1) {
            int t = (tid >= d) ? s[tid - d] : 0;
            __syncthreads();
            s[tid] += t;
            __syncthreads();
        }
        int carry = carry_s;
        if (i < B) offs[i] = carry + s[tid] - v;
        __syncthreads();
        if (tid == 0) carry_s = carry + s[255];
        __syncthreads();
    }
    if (tid == 0) ptr[N] = carry_s;
}

__global__ __launch_bounds__(256) void scan2_kernel(
    const int* __restrict__ indeg, const int* __restrict__ offs,
    int* __restrict__ ptr, int* __restrict__ cursor, int N)
{
    __shared__ int s[256];
    int tid = threadIdx.x;
    int i = blockIdx.x * 256 + tid;
    int v = (i < N) ? indeg[i] : 0;
    s[tid] = v;
    __syncthreads();
    for (int d = 1; d < 256; d <<= 1) {
        int t = (tid >= d) ? s[tid - d] : 0;
        __syncthreads();
        s[tid] += t;
        __syncthreads();
    }
    if (i < N) {
        int ex = offs[blockIdx.x] + s[tid] - v;
        ptr[i] = ex;
        cursor[i] = ex;
    }
}

// ---------------- CSR fill + per-edge record {row, ci, norm} ----------------
__global__ void fillcsr_kernel(const int* __restrict__ ei, const int* __restrict__ attr,
                               const float* __restrict__ dis, int* __restrict__ cursor,
                               int4* __restrict__ edata, int E)
{
    for (int e = blockIdx.x * blockDim.x + threadIdx.x; e < E; e += gridDim.x * blockDim.x) {
        int r   = ei[e];
        int col = ei[E + e];
        int pos = atomicAdd(&cursor[col], 1);
        int ci  = attr[e * 3] * 12 + attr[e * 3 + 1] * 2 + attr[e * 3 + 2];
        float nrm = dis[r] * dis[col];
        int4 ed;
        ed.x = r; ed.y = ci; ed.z = __builtin_bit_cast(int, nrm); ed.w = 0;
        edata[pos] = ed;
    }
}

// ---------------- graph boundaries: gptr[g] = lower_bound(batch, g) ----------
__global__ void gptr_kernel(const int* __restrict__ batch, int* __restrict__ gptr,
                            int N, int G)
{
    int n = blockIdx.x * blockDim.x + threadIdx.x;
    if (n >= N) return;
    int b = batch[n];
    int bp = (n == 0) ? -1 : batch[n - 1];
    for (int g = bp + 1; g <= b; ++g) gptr[g] = n;
    if (n == N - 1)
        for (int g = b + 1; g <= G; ++g) gptr[g] = N;
}

// ---------------- z = h @ W^T + b  (bf16 MFMA; LDS-repacked coalesced stores) --
__global__ __launch_bounds__(256) void gemm_kernel(
    const unsigned short* __restrict__ hb, const unsigned short* __restrict__ Wb,
    const float* __restrict__ bias, unsigned short* __restrict__ zb, int N)
{
    __shared__ unsigned short st[128][132];   // +4 pad: break power-of-2 bank stride
    int wave = threadIdx.x >> 6;
    int lane = threadIdx.x & 63;
    int l15 = lane & 15;
    int q = lane >> 4;
    long row0 = (long)blockIdx.x * 128 + wave * 32;

    short8 a[2][4];
#pragma unroll
    for (int mt = 0; mt < 2; ++mt) {
        long rl = row0 + mt * 16 + l15;
        if (rl > (long)N - 1) rl = (long)N - 1;   // clamp tail (stores guarded)
        const unsigned short* ap = hb + rl * HID + q * 8;
#pragma unroll
        for (int kb = 0; kb < 4; ++kb)
            a[mt][kb] = *reinterpret_cast<const short8*>(ap + kb * 32);
    }

    floatx4 acc[2][8];
#pragma unroll
    for (int mt = 0; mt < 2; ++mt)
#pragma unroll
        for (int nt = 0; nt < 8; ++nt) {
            floatx4 zz = {0.f, 0.f, 0.f, 0.f};
            acc[mt][nt] = zz;
        }

#pragma unroll
    for (int nt = 0; nt < 8; ++nt) {
        const unsigned short* bp = Wb + (nt * 16 + l15) * HID + q * 8;
#pragma unroll
        for (int kb = 0; kb < 4; ++kb) {
            short8 b = *reinterpret_cast<const short8*>(bp + kb * 32);
            acc[0][nt] = __builtin_amdgcn_mfma_f32_16x16x32_bf16(a[0][kb], b, acc[0][nt], 0, 0, 0);
            acc[1][nt] = __builtin_amdgcn_mfma_f32_16x16x32_bf16(a[1][kb], b, acc[1][nt], 0, 0, 0);
        }
    }

    float bi[8];
#pragma unroll
    for (int nt = 0; nt < 8; ++nt) bi[nt] = bias[nt * 16 + l15];

    // C/D layout (m89/m91): row = q*4 + reg, col = l15 + 16*nt -> LDS
#pragma unroll
    for (int mt = 0; mt < 2; ++mt)
#pragma unroll
        for (int r = 0; r < 4; ++r) {
            int lr = wave * 32 + mt * 16 + q * 4 + r;
#pragma unroll
            for (int nt = 0; nt < 8; ++nt)
                st[lr][l15 + 16 * nt] = f2bf(acc[mt][nt][r] + bi[nt]);
        }
    __syncthreads();

    // coalesced store: per iteration, 256 threads cover a contiguous 4 KB (16 rows)
    int tr = threadIdx.x >> 4;        // 0..15
    int tc = (threadIdx.x & 15) * 8;  // col in ushorts
#pragma unroll
    for (int i = 0; i < 8; ++i) {
        int row = i * 16 + tr;
        long gr = (long)blockIdx.x * 128 + row;
        if (gr < N) {
            ushort8v v = *reinterpret_cast<const ushort8v*>(&st[row][tc]);
            *reinterpret_cast<ushort8v*>(zb + gr * HID + tc) = v;
        }
    }
}

// ---------------- fused: self-term + CSR gather + relu + BN + combine -------
template<bool FIRST>
__global__ __launch_bounds__(256) void agg_kernel(
    const int* __restrict__ ptr, const int4* __restrict__ edata,
    const float* __restrict__ comb,
    const float* __restrict__ rdeg, const float* __restrict__ root,
    const float* __restrict__ gamma, const float* __restrict__ beta,
    const float* __restrict__ mean, const float* __restrict__ var,
    const unsigned short* __restrict__ zb, unsigned short* __restrict__ hb,
    float fi, int N)
{
    int n = blockIdx.x * 8 + (threadIdx.x >> 5);
    if (n >= N) return;
    int c = (threadIdx.x & 31) * 4;

    ushort4v zv = *reinterpret_cast<const ushort4v*>(zb + (long)n * HID + c);
    floatx4 rt = *reinterpret_cast<const floatx4*>(root + c);
    float rd = rdeg[n];
    floatx4 acc;
#pragma unroll
    for (int j = 0; j < 4; ++j) acc[j] = fmaxf(bf2f(zv[j]) + rt[j], 0.f) * rd;

    int jb = ptr[n], je = ptr[n + 1];
    for (int j2 = jb; j2 < je; ++j2) {
        int4 ed = edata[j2];                         // broadcast 16 B
        float nrm = __builtin_bit_cast(float, ed.z);
        floatx4 ev = *reinterpret_cast<const floatx4*>(comb + ed.y * HID + c);
        ushort4v zr = *reinterpret_cast<const ushort4v*>(zb + (long)ed.x * HID + c);
#pragma unroll
        for (int j = 0; j < 4; ++j) acc[j] += fmaxf(bf2f(zr[j]) + ev[j], 0.f) * nrm;
    }

    floatx4 gm = *reinterpret_cast<const floatx4*>(gamma + c);
    floatx4 bt = *reinterpret_cast<const floatx4*>(beta + c);
    floatx4 mn = *reinterpret_cast<const floatx4*>(mean + c);
    floatx4 vr = *reinterpret_cast<const floatx4*>(var + c);
    unsigned short* hp = hb + (long)n * HID + c;
    ushort4v hv;
    if constexpr (!FIRST) hv = *reinterpret_cast<const ushort4v*>(hp);
    ushort4v o;
#pragma unroll
    for (int j = 0; j < 4; ++j) {
        float t = fmaxf(acc[j], 0.f);
        t = (t - mn[j]) * (gm[j] * rsqrtf(vr[j] + 1e-5f)) + bt[j];
        float hn;
        if constexpr (FIRST) hn = t;                 // fi = 0
        else hn = fi * bf2f(hv[j]) + (1.f - fi) * t;
        o[j] = f2bf(hn);
    }
    *reinterpret_cast<ushort4v*>(hp) = o;
}

// ---------------- fused mean-pool + final linear (gptr, vectorized) ----------
__global__ __launch_bounds__(128) void poollin_kernel(
    const unsigned short* __restrict__ hb, const int* __restrict__ gptr,
    const float* __restrict__ lin_W, const float* __restrict__ lin_b,
    float* __restrict__ out, int G)
{
    int g = blockIdx.x;
    if (g >= G) return;
    int t = threadIdx.x;
    int lo = gptr[g], hi = gptr[g + 1];
    int c = (t & 31) * 4;
    int sub = t >> 5;                  // 4 node-lanes
    floatx4 s = {0.f, 0.f, 0.f, 0.f};
    for (int n = lo + sub; n < hi; n += 4) {
        ushort4v hv = *reinterpret_cast<const ushort4v*>(hb + (long)n * HID + c);
#pragma unroll
        for (int j = 0; j < 4; ++j) s[j] += bf2f(hv[j]);
    }
    __shared__ float ps[4][HID];
    *reinterpret_cast<floatx4*>(&ps[sub][c]) = s;
    __syncthreads();
    __shared__ float p[HID];
    float cnt = (hi > lo) ? (float)(hi - lo) : 1.f;
    p[t] = (ps[0][t] + ps[1][t] + ps[2][t] + ps[3][t]) / cnt;
    __syncthreads();
    float acc = lin_b[t];
#pragma unroll 8
    for (int k = 0; k < HID; ++k) acc += p[k] * lin_W[t * HID + k];
    out[(long)g * HID + t] = acc;
}

extern "C" void kernel_launch(void* const* d_in, const int* in_sizes, int n_in,
                              void* d_out, int out_size, void* d_ws, size_t ws_size,
                              hipStream_t stream)
{
    const int* x          = (const int*)d_in[0];
    const int* ei         = (const int*)d_in[1];
    const int* attr       = (const int*)d_in[2];
    const int* batch      = (const int*)d_in[3];
    const float* atom_emb = (const float*)d_in[4];
    const float* bond_emb = (const float*)d_in[5];
    const float* conv_W   = (const float*)d_in[6];
    const float* conv_b   = (const float*)d_in[7];
    const float* root     = (const float*)d_in[8];
    const float* gamma    = (const float*)d_in[9];
    const float* beta     = (const float*)d_in[10];
    const float* mean     = (const float*)d_in[11];
    const float* var      = (const float*)d_in[12];
    const float* lin_W    = (const float*)d_in[13];
    const float* lin_b    = (const float*)d_in[14];
    float* out = (float*)d_out;

    const int N = in_sizes[0] / 9;
    const int E = in_sizes[1] / 2;
    const int G = out_size / HID;
    const int B = (N + 255) / 256;

    auto al = [](size_t b) { return (b + 255) & ~(size_t)255; };
    const size_t need =
        al((size_t)N * HID * 2) +     // hb
        al((size_t)N * HID * 2) +     // zb
        al((size_t)(N + 1) * 4) +     // ptr
        al((size_t)N * 4) +           // cursor
        al((size_t)E * 16) +          // edata
        al((size_t)N * 4) +           // indeg
        al((size_t)2048 * 4) * 2 +    // partial + offs
        al((size_t)N * 4) * 2 +       // rdeg + dis
        al((size_t)(G + 1) * 4) +     // gptr
        al((size_t)60 * HID * 4) +    // comb
        al((size_t)HID * HID * 2);    // Wb

    if (ws_size < need || B > 2048) {
        float v = (B > 2048) ? 3000.f : (1000.f + (float)(ws_size >> 20));
        long n = (long)out_size;
        diag_kernel<<<(int)((n + 255) / 256), 256, 0, stream>>>(out, n, v);
        return;
    }

    char* wsp = (char*)d_ws;
    size_t used = 0;
    auto alloc = [&](size_t bytes) { char* p = wsp + used; used += al(bytes); return p; };
    unsigned short* hb = (unsigned short*)alloc((size_t)N * HID * 2);
    unsigned short* zb = (unsigned short*)alloc((size_t)N * HID * 2);
    int* ptr     = (int*)alloc((size_t)(N + 1) * 4);
    int* cursor  = (int*)alloc((size_t)N * 4);
    int4* edata  = (int4*)alloc((size_t)E * 16);
    int* indeg   = (int*)alloc((size_t)N * 4);
    int* partial = (int*)alloc((size_t)2048 * 4);
    int* offs    = (int*)alloc((size_t)2048 * 4);
    float* rdeg  = (float*)alloc((size_t)N * 4);
    float* dis   = (float*)alloc((size_t)N * 4);
    int* gptr    = (int*)alloc((size_t)(G + 1) * 4);
    float* comb  = (float*)alloc((size_t)60 * HID * 4);
    unsigned short* Wb = (unsigned short*)alloc((size_t)HID * HID * 2);

    // ---- prologue ----
    fill0f_kernel<<<(N + 255) / 256, 256, 0, stream>>>(rdeg, N);
    fill0i_kernel<<<(N + 255) / 256, 256, 0, stream>>>(indeg, N);
    cvtW_kernel<<<(HID * HID + 255) / 256, 256, 0, stream>>>(conv_W, Wb);
    combemb_kernel<<<60, 128, 0, stream>>>(bond_emb, comb);
    encode_kernel<<<N, 128, 0, stream>>>(x, atom_emb, hb, N);
    hist_kernel<<<1024, 256, 0, stream>>>(ei, rdeg, indeg, E);
    fdeg_kernel<<<(N + 255) / 256, 256, 0, stream>>>(rdeg, dis, N);
    bsum_kernel<<<B, 256, 0, stream>>>(indeg, partial, N);
    scan1_kernel<<<1, 256, 0, stream>>>(partial, offs, ptr, B, N);
    scan2_kernel<<<B, 256, 0, stream>>>(indeg, offs, ptr, cursor, N);
    fillcsr_kernel<<<1024, 256, 0, stream>>>(ei, attr, dis, cursor, edata, E);
    gptr_kernel<<<(N + 255) / 256, 256, 0, stream>>>(batch, gptr, N, G);

    // ---- loop (i=1 is identity: h = 1*old + 0*z, skipped) ----
    const float fis[4] = {0.f, 2.f, 3.f, 4.f};
    const int gemm_blocks = (N + 127) / 128;
    const int agg_blocks = (N + 7) / 8;
    for (int t = 0; t < 4; ++t) {
        gemm_kernel<<<gemm_blocks, 256, 0, stream>>>(hb, Wb, conv_b, zb, N);
        if (t == 0)
            agg_kernel<true ><<<agg_blocks, 256, 0, stream>>>(ptr, edata, comb, rdeg, root,
                                                              gamma, beta, mean, var,
                                                              zb, hb, fis[t], N);
        else
            agg_kernel<false><<<agg_blocks, 256, 0, stream>>>(ptr, edata, comb, rdeg, root,
                                                              gamma, beta, mean, var,
                                                              zb, hb, fis[t], N);
    }

    // ---- fused mean-pool + output linear ----
    poollin_kernel<<<G, 128, 0, stream>>>(hb, gptr, lin_W, lin_b, out, G);
}

// Round 8
// 865.512 us; speedup vs baseline: 2.9902x; 1.1219x over previous
//
#include <hip/hip_runtime.h>

#define HID 128

typedef __attribute__((ext_vector_type(8))) short short8;
typedef __attribute__((ext_vector_type(8))) unsigned short ushort8v;
typedef __attribute__((ext_vector_type(4))) float floatx4;
typedef __attribute__((ext_vector_type(4))) unsigned short ushort4v;

__device__ __forceinline__ unsigned short f2bf(float f) {
    unsigned u = __builtin_bit_cast(unsigned, f);
    u += 0x7FFF + ((u >> 16) & 1);           // RNE
    return (unsigned short)(u >> 16);
}
__device__ __forceinline__ float bf2f(unsigned short s) {
    unsigned u = ((unsigned)s) << 16;
    return __builtin_bit_cast(float, u);
}

// ---------------- merged fill: rdeg (f32 0) + indeg (i32 0) ----------------
__global__ void fillrd_kernel(float* __restrict__ rdeg, int* __restrict__ indeg, int N)
{
    int i = blockIdx.x * 256 + threadIdx.x;
    if (i < N) { rdeg[i] = 0.f; indeg[i] = 0; }
}

// ---------------- diagnostic ----------------
__global__ void diag_kernel(float* __restrict__ out, long n, float val)
{
    long i = (long)blockIdx.x * blockDim.x + threadIdx.x;
    if (i < n) out[i] = val;
}

// ---------------- atom encoder: 8 nodes/block, 32 lanes x 4 cols -------------
__global__ __launch_bounds__(256) void encode_kernel(
    const int* __restrict__ x, const float* __restrict__ atom_emb,
    unsigned short* __restrict__ hb, int N)
{
    int n = blockIdx.x * 8 + (threadIdx.x >> 5);
    if (n >= N) return;
    int c = (threadIdx.x & 31) * 4;
    const int OFF[9] = {0, 119, 123, 135, 147, 157, 163, 169, 171};
    floatx4 s = {0.f, 0.f, 0.f, 0.f};
#pragma unroll
    for (int f = 0; f < 9; ++f) {
        int idx = x[n * 9 + f] + OFF[f];                      // lane-broadcast load
        floatx4 v = *reinterpret_cast<const floatx4*>(atom_emb + (long)idx * HID + c);
#pragma unroll
        for (int j = 0; j < 4; ++j) s[j] += v[j];
    }
    ushort4v o;
#pragma unroll
    for (int j = 0; j < 4; ++j) o[j] = f2bf(s[j]);
    *reinterpret_cast<ushort4v*>(hb + (long)n * HID + c) = o;
}

// ---------------- fp32 -> bf16 table convert ----------------
__global__ void cvtW_kernel(const float* __restrict__ W, unsigned short* __restrict__ Wb)
{
    int i = blockIdx.x * 256 + threadIdx.x;
    if (i < HID * HID) Wb[i] = f2bf(W[i]);
}

// ---------------- bond combo table: 60 x 128 (fp32) ----------------
__global__ __launch_bounds__(128) void combemb_kernel(
    const float* __restrict__ bond_emb, float* __restrict__ comb)
{
    int i = blockIdx.x;
    int c = threadIdx.x;
    int a0 = i / 12, a1 = (i % 12) / 2, a2 = i % 2;
    comb[i * HID + c] = bond_emb[a0 * HID + c] + bond_emb[(5 + a1) * HID + c]
                      + bond_emb[(11 + a2) * HID + c];
}

// ---------------- merged: out-degree (row) + in-degree histogram (col) -------
__global__ void hist_kernel(const int* __restrict__ ei, float* __restrict__ deg,
                            int* __restrict__ indeg, int E)
{
    for (int e = blockIdx.x * blockDim.x + threadIdx.x; e < E; e += gridDim.x * blockDim.x) {
        atomicAdd(&deg[ei[e]], 1.f);
        atomicAdd(&indeg[ei[E + e]], 1);
    }
}

// deg -> rdeg (1/deg) in place, dis = deg^-0.5
__global__ void fdeg_kernel(float* __restrict__ deg, float* __restrict__ dis, int N)
{
    int n = blockIdx.x * blockDim.x + threadIdx.x;
    if (n < N) {
        float d = deg[n] + 1.f;
        deg[n] = 1.f / d;
        dis[n] = rsqrtf(d);
    }
}

// ---------------- CSR scan chain ----------------
__global__ __launch_bounds__(256) void bsum_kernel(
    const int* __restrict__ indeg, int* __restrict__ partial, int N)
{
    __shared__ int s[256];
    int i = blockIdx.x * 256 + threadIdx.x;
    s[threadIdx.x] = (i < N) ? indeg[i] : 0;
    __syncthreads();
    for (int d = 128; d > 0; d >>= 1) {
        if (threadIdx.x < d) s[threadIdx.x] += s[threadIdx.x + d];
        __syncthreads();
    }
    if (threadIdx.x == 0) partial[blockIdx.x] = s[0];
}

__global__ __launch_bounds__(256) void scan1_kernel(
    const int* __restrict__ partial, int* __restrict__ offs,
    int* __restrict__ ptr, int B, int N)
{
    __shared__ int s[256];
    __shared__ int carry_s;
    int tid = threadIdx.x;
    if (tid == 0) carry_s = 0;
    __syncthreads();
    for (int base = 0; base < B; base += 256) {
        int i = base + tid;
        int v = (i < B) ? partial[i] : 0;
        s[tid] = v;
        __syncthreads();
        for (int d = 1; d < 256; d <<= 1) {
            int t = (tid >= d) ? s[tid - d] : 0;
            __syncthreads();
            s[tid] += t;
            __syncthreads();
        }
        int carry = carry_s;
        if (i < B) offs[i] = carry + s[tid] - v;
        __syncthreads();
        if (tid == 0) carry_s = carry + s[255];
        __syncthreads();
    }
    if (tid == 0) ptr[N] = carry_s;
}

__global__ __launch_bounds__(256) void scan2_kernel(
    const int* __restrict__ indeg, const int* __restrict__ offs,
    int* __restrict__ ptr, int* __restrict__ cursor, int N)
{
    __shared__ int s[256];
    int tid = threadIdx.x;
    int i = blockIdx.x * 256 + tid;
    int v = (i < N) ? indeg[i] : 0;
    s[tid] = v;
    __syncthreads();
    for (int d = 1; d < 256; d <<= 1) {
        int t = (tid >= d) ? s[tid - d] : 0;
        __syncthreads();
        s[tid] += t;
        __syncthreads();
    }
    if (i < N) {
        int ex = offs[blockIdx.x] + s[tid] - v;
        ptr[i] = ex;
        cursor[i] = ex;
    }
}

// ---------------- CSR fill + per-edge record {row, ci, norm} ----------------
__global__ void fillcsr_kernel(const int* __restrict__ ei, const int* __restrict__ attr,
                               const float* __restrict__ dis, int* __restrict__ cursor,
                               int4* __restrict__ edata, int E)
{
    for (int e = blockIdx.x * blockDim.x + threadIdx.x; e < E; e += gridDim.x * blockDim.x) {
        int r   = ei[e];
        int col = ei[E + e];
        int pos = atomicAdd(&cursor[col], 1);
        int ci  = attr[e * 3] * 12 + attr[e * 3 + 1] * 2 + attr[e * 3 + 2];
        float nrm = dis[r] * dis[col];
        int4 ed;
        ed.x = r; ed.y = ci; ed.z = __builtin_bit_cast(int, nrm); ed.w = 0;
        edata[pos] = ed;
    }
}

// ---------------- graph boundaries: gptr[g] = lower_bound(batch, g) ----------
__global__ void gptr_kernel(const int* __restrict__ batch, int* __restrict__ gptr,
                            int N, int G)
{
    int n = blockIdx.x * blockDim.x + threadIdx.x;
    if (n >= N) return;
    int b = batch[n];
    int bp = (n == 0) ? -1 : batch[n - 1];
    for (int g = bp + 1; g <= b; ++g) gptr[g] = n;
    if (n == N - 1)
        for (int g = b + 1; g <= G; ++g) gptr[g] = N;
}

// ---------------- z = h @ W^T + b  (bf16 MFMA; LDS-repacked coalesced stores) --
__global__ __launch_bounds__(256) void gemm_kernel(
    const unsigned short* __restrict__ hb, const unsigned short* __restrict__ Wb,
    const float* __restrict__ bias, unsigned short* __restrict__ zb, int N)
{
    __shared__ unsigned short st[128][132];   // +4 pad
    int wave = threadIdx.x >> 6;
    int lane = threadIdx.x & 63;
    int l15 = lane & 15;
    int q = lane >> 4;
    long row0 = (long)blockIdx.x * 128 + wave * 32;

    short8 a[2][4];
#pragma unroll
    for (int mt = 0; mt < 2; ++mt) {
        long rl = row0 + mt * 16 + l15;
        if (rl > (long)N - 1) rl = (long)N - 1;
        const unsigned short* ap = hb + rl * HID + q * 8;
#pragma unroll
        for (int kb = 0; kb < 4; ++kb)
            a[mt][kb] = *reinterpret_cast<const short8*>(ap + kb * 32);
    }

    floatx4 acc[2][8];
#pragma unroll
    for (int mt = 0; mt < 2; ++mt)
#pragma unroll
        for (int nt = 0; nt < 8; ++nt) {
            floatx4 zz = {0.f, 0.f, 0.f, 0.f};
            acc[mt][nt] = zz;
        }

#pragma unroll
    for (int nt = 0; nt < 8; ++nt) {
        const unsigned short* bp = Wb + (nt * 16 + l15) * HID + q * 8;
#pragma unroll
        for (int kb = 0; kb < 4; ++kb) {
            short8 b = *reinterpret_cast<const short8*>(bp + kb * 32);
            acc[0][nt] = __builtin_amdgcn_mfma_f32_16x16x32_bf16(a[0][kb], b, acc[0][nt], 0, 0, 0);
            acc[1][nt] = __builtin_amdgcn_mfma_f32_16x16x32_bf16(a[1][kb], b, acc[1][nt], 0, 0, 0);
        }
    }

    float bi[8];
#pragma unroll
    for (int nt = 0; nt < 8; ++nt) bi[nt] = bias[nt * 16 + l15];

#pragma unroll
    for (int mt = 0; mt < 2; ++mt)
#pragma unroll
        for (int r = 0; r < 4; ++r) {
            int lr = wave * 32 + mt * 16 + q * 4 + r;
#pragma unroll
            for (int nt = 0; nt < 8; ++nt)
                st[lr][l15 + 16 * nt] = f2bf(acc[mt][nt][r] + bi[nt]);
        }
    __syncthreads();

    int tr = threadIdx.x >> 4;
    int tc = (threadIdx.x & 15) * 8;
#pragma unroll
    for (int i = 0; i < 8; ++i) {
        int row = i * 16 + tr;
        long gr = (long)blockIdx.x * 128 + row;
        if (gr < N) {
            ushort8v v = *reinterpret_cast<const ushort8v*>(&st[row][tc]);
            *reinterpret_cast<ushort8v*>(zb + gr * HID + tc) = v;
        }
    }
}

// ---------------- final linear via MFMA: out = pooled @ lin_W^T + lin_b (fp32) --
__global__ __launch_bounds__(256) void linmm_kernel(
    const unsigned short* __restrict__ pb, const unsigned short* __restrict__ Wb,
    const float* __restrict__ bias, float* __restrict__ out, int G)
{
    int wave = threadIdx.x >> 6;
    int lane = threadIdx.x & 63;
    int l15 = lane & 15;
    int q = lane >> 4;
    long row0 = (long)blockIdx.x * 128 + wave * 32;

    short8 a[2][4];
#pragma unroll
    for (int mt = 0; mt < 2; ++mt) {
        long rl = row0 + mt * 16 + l15;
        if (rl > (long)G - 1) rl = (long)G - 1;
        const unsigned short* ap = pb + rl * HID + q * 8;
#pragma unroll
        for (int kb = 0; kb < 4; ++kb)
            a[mt][kb] = *reinterpret_cast<const short8*>(ap + kb * 32);
    }

    floatx4 acc[2][8];
#pragma unroll
    for (int mt = 0; mt < 2; ++mt)
#pragma unroll
        for (int nt = 0; nt < 8; ++nt) {
            floatx4 zz = {0.f, 0.f, 0.f, 0.f};
            acc[mt][nt] = zz;
        }

#pragma unroll
    for (int nt = 0; nt < 8; ++nt) {
        const unsigned short* bp = Wb + (nt * 16 + l15) * HID + q * 8;
#pragma unroll
        for (int kb = 0; kb < 4; ++kb) {
            short8 b = *reinterpret_cast<const short8*>(bp + kb * 32);
            acc[0][nt] = __builtin_amdgcn_mfma_f32_16x16x32_bf16(a[0][kb], b, acc[0][nt], 0, 0, 0);
            acc[1][nt] = __builtin_amdgcn_mfma_f32_16x16x32_bf16(a[1][kb], b, acc[1][nt], 0, 0, 0);
        }
    }

    float bi[8];
#pragma unroll
    for (int nt = 0; nt < 8; ++nt) bi[nt] = bias[nt * 16 + l15];

    // fp32 direct store (only ~94 blocks; no need to repack)
#pragma unroll
    for (int mt = 0; mt < 2; ++mt)
#pragma unroll
        for (int r = 0; r < 4; ++r) {
            long rr = row0 + mt * 16 + q * 4 + r;
            if (rr < G) {
                float* op = out + rr * HID + l15;
#pragma unroll
                for (int nt = 0; nt < 8; ++nt)
                    op[nt * 16] = acc[mt][nt][r] + bi[nt];
            }
        }
}

// ---------------- fused: self-term + CSR gather + relu + BN + combine -------
template<bool FIRST>
__global__ __launch_bounds__(256) void agg_kernel(
    const int* __restrict__ ptr, const int4* __restrict__ edata,
    const float* __restrict__ comb,
    const float* __restrict__ rdeg, const float* __restrict__ root,
    const float* __restrict__ gamma, const float* __restrict__ beta,
    const float* __restrict__ mean, const float* __restrict__ var,
    const unsigned short* __restrict__ zb, unsigned short* __restrict__ hb,
    float fi, int N)
{
    int n = blockIdx.x * 8 + (threadIdx.x >> 5);
    if (n >= N) return;
    int c = (threadIdx.x & 31) * 4;

    ushort4v zv = *reinterpret_cast<const ushort4v*>(zb + (long)n * HID + c);
    floatx4 rt = *reinterpret_cast<const floatx4*>(root + c);
    float rd = rdeg[n];
    floatx4 acc;
#pragma unroll
    for (int j = 0; j < 4; ++j) acc[j] = fmaxf(bf2f(zv[j]) + rt[j], 0.f) * rd;

    int jb = ptr[n], je = ptr[n + 1];
    for (int j2 = jb; j2 < je; ++j2) {
        int4 ed = edata[j2];                         // broadcast 16 B
        float nrm = __builtin_bit_cast(float, ed.z);
        floatx4 ev = *reinterpret_cast<const floatx4*>(comb + ed.y * HID + c);
        ushort4v zr = *reinterpret_cast<const ushort4v*>(zb + (long)ed.x * HID + c);
#pragma unroll
        for (int j = 0; j < 4; ++j) acc[j] += fmaxf(bf2f(zr[j]) + ev[j], 0.f) * nrm;
    }

    floatx4 gm = *reinterpret_cast<const floatx4*>(gamma + c);
    floatx4 bt = *reinterpret_cast<const floatx4*>(beta + c);
    floatx4 mn = *reinterpret_cast<const floatx4*>(mean + c);
    floatx4 vr = *reinterpret_cast<const floatx4*>(var + c);
    unsigned short* hp = hb + (long)n * HID + c;
    ushort4v hv;
    if constexpr (!FIRST) hv = *reinterpret_cast<const ushort4v*>(hp);
    ushort4v o;
#pragma unroll
    for (int j = 0; j < 4; ++j) {
        float t = fmaxf(acc[j], 0.f);
        t = (t - mn[j]) * (gm[j] * rsqrtf(vr[j] + 1e-5f)) + bt[j];
        float hn;
        if constexpr (FIRST) hn = t;                 // fi = 0
        else hn = fi * bf2f(hv[j]) + (1.f - fi) * t;
        o[j] = f2bf(hn);
    }
    *reinterpret_cast<ushort4v*>(hp) = o;
}

// ---------------- mean-pool per graph -> bf16 pooled[G][128] ----------------
__global__ __launch_bounds__(256) void pool_kernel(
    const unsigned short* __restrict__ hb, const int* __restrict__ gptr,
    unsigned short* __restrict__ pb, int G)
{
    int g = blockIdx.x;
    if (g >= G) return;
    int tid = threadIdx.x;
    int sub = tid >> 5;                // 8 node-lanes
    int c = (tid & 31) * 4;
    int lo = gptr[g], hi = gptr[g + 1];
    floatx4 s = {0.f, 0.f, 0.f, 0.f};
    for (int n = lo + sub; n < hi; n += 8) {
        ushort4v hv = *reinterpret_cast<const ushort4v*>(hb + (long)n * HID + c);
#pragma unroll
        for (int j = 0; j < 4; ++j) s[j] += bf2f(hv[j]);
    }
    __shared__ float ps[8][HID];
    *reinterpret_cast<floatx4*>(&ps[sub][c]) = s;
    __syncthreads();
    if (tid < HID) {
        float sum = 0.f;
#pragma unroll
        for (int k = 0; k < 8; ++k) sum += ps[k][tid];
        float cnt = (hi > lo) ? (float)(hi - lo) : 1.f;
        pb[(long)g * HID + tid] = f2bf(sum / cnt);
    }
}

extern "C" void kernel_launch(void* const* d_in, const int* in_sizes, int n_in,
                              void* d_out, int out_size, void* d_ws, size_t ws_size,
                              hipStream_t stream)
{
    const int* x          = (const int*)d_in[0];
    const int* ei         = (const int*)d_in[1];
    const int* attr       = (const int*)d_in[2];
    const int* batch      = (const int*)d_in[3];
    const float* atom_emb = (const float*)d_in[4];
    const float* bond_emb = (const float*)d_in[5];
    const float* conv_W   = (const float*)d_in[6];
    const float* conv_b   = (const float*)d_in[7];
    const float* root     = (const float*)d_in[8];
    const float* gamma    = (const float*)d_in[9];
    const float* beta     = (const float*)d_in[10];
    const float* mean     = (const float*)d_in[11];
    const float* var      = (const float*)d_in[12];
    const float* lin_W    = (const float*)d_in[13];
    const float* lin_b    = (const float*)d_in[14];
    float* out = (float*)d_out;

    const int N = in_sizes[0] / 9;
    const int E = in_sizes[1] / 2;
    const int G = out_size / HID;
    const int B = (N + 255) / 256;

    auto al = [](size_t b) { return (b + 255) & ~(size_t)255; };
    const size_t need =
        al((size_t)N * HID * 2) +     // hb
        al((size_t)N * HID * 2) +     // zb
        al((size_t)(N + 1) * 4) +     // ptr
        al((size_t)N * 4) +           // cursor
        al((size_t)E * 16) +          // edata
        al((size_t)N * 4) +           // indeg
        al((size_t)2048 * 4) * 2 +    // partial + offs
        al((size_t)N * 4) * 2 +       // rdeg + dis
        al((size_t)(G + 1) * 4) +     // gptr
        al((size_t)(G + 128) * HID * 2) + // pooled bf16 (+tail pad for linmm clamp)
        al((size_t)60 * HID * 4) +    // comb
        al((size_t)HID * HID * 2) * 2; // Wb + linWb

    if (ws_size < need || B > 2048) {
        float v = (B > 2048) ? 3000.f : (1000.f + (float)(ws_size >> 20));
        long n = (long)out_size;
        diag_kernel<<<(int)((n + 255) / 256), 256, 0, stream>>>(out, n, v);
        return;
    }

    char* wsp = (char*)d_ws;
    size_t used = 0;
    auto alloc = [&](size_t bytes) { char* p = wsp + used; used += al(bytes); return p; };
    unsigned short* hb = (unsigned short*)alloc((size_t)N * HID * 2);
    unsigned short* zb = (unsigned short*)alloc((size_t)N * HID * 2);
    int* ptr     = (int*)alloc((size_t)(N + 1) * 4);
    int* cursor  = (int*)alloc((size_t)N * 4);
    int4* edata  = (int4*)alloc((size_t)E * 16);
    int* indeg   = (int*)alloc((size_t)N * 4);
    int* partial = (int*)alloc((size_t)2048 * 4);
    int* offs    = (int*)alloc((size_t)2048 * 4);
    float* rdeg  = (float*)alloc((size_t)N * 4);
    float* dis   = (float*)alloc((size_t)N * 4);
    int* gptr    = (int*)alloc((size_t)(G + 1) * 4);
    unsigned short* pb = (unsigned short*)alloc((size_t)(G + 128) * HID * 2);
    float* comb  = (float*)alloc((size_t)60 * HID * 4);
    unsigned short* Wb    = (unsigned short*)alloc((size_t)HID * HID * 2);
    unsigned short* linWb = (unsigned short*)alloc((size_t)HID * HID * 2);

    // ---- prologue ----
    fillrd_kernel<<<B, 256, 0, stream>>>(rdeg, indeg, N);
    cvtW_kernel<<<(HID * HID + 255) / 256, 256, 0, stream>>>(conv_W, Wb);
    cvtW_kernel<<<(HID * HID + 255) / 256, 256, 0, stream>>>(lin_W, linWb);
    combemb_kernel<<<60, 128, 0, stream>>>(bond_emb, comb);
    encode_kernel<<<(N + 7) / 8, 256, 0, stream>>>(x, atom_emb, hb, N);
    hist_kernel<<<1024, 256, 0, stream>>>(ei, rdeg, indeg, E);
    fdeg_kernel<<<B, 256, 0, stream>>>(rdeg, dis, N);
    bsum_kernel<<<B, 256, 0, stream>>>(indeg, partial, N);
    scan1_kernel<<<1, 256, 0, stream>>>(partial, offs, ptr, B, N);
    scan2_kernel<<<B, 256, 0, stream>>>(indeg, offs, ptr, cursor, N);
    fillcsr_kernel<<<1024, 256, 0, stream>>>(ei, attr, dis, cursor, edata, E);
    gptr_kernel<<<B, 256, 0, stream>>>(batch, gptr, N, G);

    // ---- loop (i=1 is identity: h = 1*old + 0*z, skipped) ----
    const float fis[4] = {0.f, 2.f, 3.f, 4.f};
    const int gemm_blocks = (N + 127) / 128;
    const int agg_blocks = (N + 7) / 8;
    for (int t = 0; t < 4; ++t) {
        gemm_kernel<<<gemm_blocks, 256, 0, stream>>>(hb, Wb, conv_b, zb, N);
        if (t == 0)
            agg_kernel<true ><<<agg_blocks, 256, 0, stream>>>(ptr, edata, comb, rdeg, root,
                                                              gamma, beta, mean, var,
                                                              zb, hb, fis[t], N);
        else
            agg_kernel<false><<<agg_blocks, 256, 0, stream>>>(ptr, edata, comb, rdeg, root,
                                                              gamma, beta, mean, var,
                                                              zb, hb, fis[t], N);
    }

    // ---- mean-pool (bf16) + MFMA final linear (fp32 out) ----
    pool_kernel<<<G, 256, 0, stream>>>(hb, gptr, pb, G);
    linmm_kernel<<<(G + 127) / 128, 256, 0, stream>>>(pb, linWb, lin_b, out, G);
}

// Round 9
// 771.722 us; speedup vs baseline: 3.3536x; 1.1215x over previous
//
#include <hip/hip_runtime.h>

#define HID 128

typedef __attribute__((ext_vector_type(8))) short short8;
typedef __attribute__((ext_vector_type(8))) unsigned short ushort8v;
typedef __attribute__((ext_vector_type(4))) float floatx4;
typedef __attribute__((ext_vector_type(4))) unsigned short ushort4v;

__device__ __forceinline__ unsigned short f2bf(float f) {
    unsigned u = __builtin_bit_cast(unsigned, f);
    u += 0x7FFF + ((u >> 16) & 1);           // RNE
    return (unsigned short)(u >> 16);
}
__device__ __forceinline__ float bf2f(unsigned short s) {
    unsigned u = ((unsigned)s) << 16;
    return __builtin_bit_cast(float, u);
}

// ---------------- merged fill: rdeg (f32 0) + indeg (i32 0) ----------------
__global__ void fillrd_kernel(float* __restrict__ rdeg, int* __restrict__ indeg, int N)
{
    int i = blockIdx.x * 256 + threadIdx.x;
    if (i < N) { rdeg[i] = 0.f; indeg[i] = 0; }
}

// ---------------- diagnostic ----------------
__global__ void diag_kernel(float* __restrict__ out, long n, float val)
{
    long i = (long)blockIdx.x * blockDim.x + threadIdx.x;
    if (i < n) out[i] = val;
}

// ---------------- atom encoder: 8 nodes/block, 32 lanes x 4 cols -------------
__global__ __launch_bounds__(256) void encode_kernel(
    const int* __restrict__ x, const float* __restrict__ atom_emb,
    unsigned short* __restrict__ hb, int N)
{
    int n = blockIdx.x * 8 + (threadIdx.x >> 5);
    if (n >= N) return;
    int c = (threadIdx.x & 31) * 4;
    const int OFF[9] = {0, 119, 123, 135, 147, 157, 163, 169, 171};
    floatx4 s = {0.f, 0.f, 0.f, 0.f};
#pragma unroll
    for (int f = 0; f < 9; ++f) {
        int idx = x[n * 9 + f] + OFF[f];                      // lane-broadcast load
        floatx4 v = *reinterpret_cast<const floatx4*>(atom_emb + (long)idx * HID + c);
#pragma unroll
        for (int j = 0; j < 4; ++j) s[j] += v[j];
    }
    ushort4v o;
#pragma unroll
    for (int j = 0; j < 4; ++j) o[j] = f2bf(s[j]);
    *reinterpret_cast<ushort4v*>(hb + (long)n * HID + c) = o;
}

// ---------------- fp32 -> bf16 table convert ----------------
__global__ void cvtW_kernel(const float* __restrict__ W, unsigned short* __restrict__ Wb)
{
    int i = blockIdx.x * 256 + threadIdx.x;
    if (i < HID * HID) Wb[i] = f2bf(W[i]);
}

// ---------------- bond combo table: 60 x 128 (fp32) ----------------
__global__ __launch_bounds__(128) void combemb_kernel(
    const float* __restrict__ bond_emb, float* __restrict__ comb)
{
    int i = blockIdx.x;
    int c = threadIdx.x;
    int a0 = i / 12, a1 = (i % 12) / 2, a2 = i % 2;
    comb[i * HID + c] = bond_emb[a0 * HID + c] + bond_emb[(5 + a1) * HID + c]
                      + bond_emb[(11 + a2) * HID + c];
}

// ---------------- merged: out-degree (row) + in-degree histogram (col) -------
__global__ void hist_kernel(const int* __restrict__ ei, float* __restrict__ deg,
                            int* __restrict__ indeg, int E)
{
    for (int e = blockIdx.x * blockDim.x + threadIdx.x; e < E; e += gridDim.x * blockDim.x) {
        atomicAdd(&deg[ei[e]], 1.f);
        atomicAdd(&indeg[ei[E + e]], 1);
    }
}

// deg -> rdeg (1/deg) in place, dis = deg^-0.5
__global__ void fdeg_kernel(float* __restrict__ deg, float* __restrict__ dis, int N)
{
    int n = blockIdx.x * blockDim.x + threadIdx.x;
    if (n < N) {
        float d = deg[n] + 1.f;
        deg[n] = 1.f / d;
        dis[n] = rsqrtf(d);
    }
}

// ---------------- CSR scan chain ----------------
__global__ __launch_bounds__(256) void bsum_kernel(
    const int* __restrict__ indeg, int* __restrict__ partial, int N)
{
    __shared__ int s[256];
    int i = blockIdx.x * 256 + threadIdx.x;
    s[threadIdx.x] = (i < N) ? indeg[i] : 0;
    __syncthreads();
    for (int d = 128; d > 0; d >>= 1) {
        if (threadIdx.x < d) s[threadIdx.x] += s[threadIdx.x + d];
        __syncthreads();
    }
    if (threadIdx.x == 0) partial[blockIdx.x] = s[0];
}

__global__ __launch_bounds__(256) void scan1_kernel(
    const int* __restrict__ partial, int* __restrict__ offs,
    int* __restrict__ ptr, int B, int N)
{
    __shared__ int s[256];
    __shared__ int carry_s;
    int tid = threadIdx.x;
    if (tid == 0) carry_s = 0;
    __syncthreads();
    for (int base = 0; base < B; base += 256) {
        int i = base + tid;
        int v = (i < B) ? partial[i] : 0;
        s[tid] = v;
        __syncthreads();
        for (int d = 1; d < 256; d <<= 1) {
            int t = (tid >= d) ? s[tid - d] : 0;
            __syncthreads();
            s[tid] += t;
            __syncthreads();
        }
        int carry = carry_s;
        if (i < B) offs[i] = carry + s[tid] - v;
        __syncthreads();
        if (tid == 0) carry_s = carry + s[255];
        __syncthreads();
    }
    if (tid == 0) ptr[N] = carry_s;
}

__global__ __launch_bounds__(256) void scan2_kernel(
    const int* __restrict__ indeg, const int* __restrict__ offs,
    int* __restrict__ ptr, int* __restrict__ cursor, int N)
{
    __shared__ int s[256];
    int tid = threadIdx.x;
    int i = blockIdx.x * 256 + tid;
    int v = (i < N) ? indeg[i] : 0;
    s[tid] = v;
    __syncthreads();
    for (int d = 1; d < 256; d <<= 1) {
        int t = (tid >= d) ? s[tid - d] : 0;
        __syncthreads();
        s[tid] += t;
        __syncthreads();
    }
    if (i < N) {
        int ex = offs[blockIdx.x] + s[tid] - v;
        ptr[i] = ex;
        cursor[i] = ex;
    }
}

// ---------------- CSR fill + per-edge record {row, ci, norm} ----------------
__global__ void fillcsr_kernel(const int* __restrict__ ei, const int* __restrict__ attr,
                               const float* __restrict__ dis, int* __restrict__ cursor,
                               int4* __restrict__ edata, int E)
{
    for (int e = blockIdx.x * blockDim.x + threadIdx.x; e < E; e += gridDim.x * blockDim.x) {
        int r   = ei[e];
        int col = ei[E + e];
        int pos = atomicAdd(&cursor[col], 1);
        int ci  = attr[e * 3] * 12 + attr[e * 3 + 1] * 2 + attr[e * 3 + 2];
        float nrm = dis[r] * dis[col];
        int4 ed;
        ed.x = r; ed.y = ci; ed.z = __builtin_bit_cast(int, nrm); ed.w = 0;
        edata[pos] = ed;
    }
}

// ---------------- graph boundaries: gptr[g] = lower_bound(batch, g) ----------
__global__ void gptr_kernel(const int* __restrict__ batch, int* __restrict__ gptr,
                            int N, int G)
{
    int n = blockIdx.x * blockDim.x + threadIdx.x;
    if (n >= N) return;
    int b = batch[n];
    int bp = (n == 0) ? -1 : batch[n - 1];
    for (int g = bp + 1; g <= b; ++g) gptr[g] = n;
    if (n == N - 1)
        for (int g = b + 1; g <= G; ++g) gptr[g] = N;
}

// ---------------- z = h @ W^T + b  (bf16 MFMA; LDS-repacked coalesced stores) --
__global__ __launch_bounds__(256) void gemm_kernel(
    const unsigned short* __restrict__ hb, const unsigned short* __restrict__ Wb,
    const float* __restrict__ bias, unsigned short* __restrict__ zb, int N)
{
    __shared__ unsigned short st[128][132];   // +4 pad
    int wave = threadIdx.x >> 6;
    int lane = threadIdx.x & 63;
    int l15 = lane & 15;
    int q = lane >> 4;
    long row0 = (long)blockIdx.x * 128 + wave * 32;

    short8 a[2][4];
#pragma unroll
    for (int mt = 0; mt < 2; ++mt) {
        long rl = row0 + mt * 16 + l15;
        if (rl > (long)N - 1) rl = (long)N - 1;
        const unsigned short* ap = hb + rl * HID + q * 8;
#pragma unroll
        for (int kb = 0; kb < 4; ++kb)
            a[mt][kb] = *reinterpret_cast<const short8*>(ap + kb * 32);
    }

    floatx4 acc[2][8];
#pragma unroll
    for (int mt = 0; mt < 2; ++mt)
#pragma unroll
        for (int nt = 0; nt < 8; ++nt) {
            floatx4 zz = {0.f, 0.f, 0.f, 0.f};
            acc[mt][nt] = zz;
        }

#pragma unroll
    for (int nt = 0; nt < 8; ++nt) {
        const unsigned short* bp = Wb + (nt * 16 + l15) * HID + q * 8;
#pragma unroll
        for (int kb = 0; kb < 4; ++kb) {
            short8 b = *reinterpret_cast<const short8*>(bp + kb * 32);
            acc[0][nt] = __builtin_amdgcn_mfma_f32_16x16x32_bf16(a[0][kb], b, acc[0][nt], 0, 0, 0);
            acc[1][nt] = __builtin_amdgcn_mfma_f32_16x16x32_bf16(a[1][kb], b, acc[1][nt], 0, 0, 0);
        }
    }

    float bi[8];
#pragma unroll
    for (int nt = 0; nt < 8; ++nt) bi[nt] = bias[nt * 16 + l15];

#pragma unroll
    for (int mt = 0; mt < 2; ++mt)
#pragma unroll
        for (int r = 0; r < 4; ++r) {
            int lr = wave * 32 + mt * 16 + q * 4 + r;
#pragma unroll
            for (int nt = 0; nt < 8; ++nt)
                st[lr][l15 + 16 * nt] = f2bf(acc[mt][nt][r] + bi[nt]);
        }
    __syncthreads();

    int tr = threadIdx.x >> 4;
    int tc = (threadIdx.x & 15) * 8;
#pragma unroll
    for (int i = 0; i < 8; ++i) {
        int row = i * 16 + tr;
        long gr = (long)blockIdx.x * 128 + row;
        if (gr < N) {
            ushort8v v = *reinterpret_cast<const ushort8v*>(&st[row][tc]);
            *reinterpret_cast<ushort8v*>(zb + gr * HID + tc) = v;
        }
    }
}

// ---------------- final linear via MFMA: out = pooled @ lin_W^T + lin_b (fp32) --
__global__ __launch_bounds__(256) void linmm_kernel(
    const unsigned short* __restrict__ pb, const unsigned short* __restrict__ Wb,
    const float* __restrict__ bias, float* __restrict__ out, int G)
{
    int wave = threadIdx.x >> 6;
    int lane = threadIdx.x & 63;
    int l15 = lane & 15;
    int q = lane >> 4;
    long row0 = (long)blockIdx.x * 128 + wave * 32;

    short8 a[2][4];
#pragma unroll
    for (int mt = 0; mt < 2; ++mt) {
        long rl = row0 + mt * 16 + l15;
        if (rl > (long)G - 1) rl = (long)G - 1;
        const unsigned short* ap = pb + rl * HID + q * 8;
#pragma unroll
        for (int kb = 0; kb < 4; ++kb)
            a[mt][kb] = *reinterpret_cast<const short8*>(ap + kb * 32);
    }

    floatx4 acc[2][8];
#pragma unroll
    for (int mt = 0; mt < 2; ++mt)
#pragma unroll
        for (int nt = 0; nt < 8; ++nt) {
            floatx4 zz = {0.f, 0.f, 0.f, 0.f};
            acc[mt][nt] = zz;
        }

#pragma unroll
    for (int nt = 0; nt < 8; ++nt) {
        const unsigned short* bp = Wb + (nt * 16 + l15) * HID + q * 8;
#pragma unroll
        for (int kb = 0; kb < 4; ++kb) {
            short8 b = *reinterpret_cast<const short8*>(bp + kb * 32);
            acc[0][nt] = __builtin_amdgcn_mfma_f32_16x16x32_bf16(a[0][kb], b, acc[0][nt], 0, 0, 0);
            acc[1][nt] = __builtin_amdgcn_mfma_f32_16x16x32_bf16(a[1][kb], b, acc[1][nt], 0, 0, 0);
        }
    }

    float bi[8];
#pragma unroll
    for (int nt = 0; nt < 8; ++nt) bi[nt] = bias[nt * 16 + l15];

#pragma unroll
    for (int mt = 0; mt < 2; ++mt)
#pragma unroll
        for (int r = 0; r < 4; ++r) {
            long rr = row0 + mt * 16 + q * 4 + r;
            if (rr < G) {
                float* op = out + rr * HID + l15;
#pragma unroll
                for (int nt = 0; nt < 8; ++nt)
                    op[nt * 16] = acc[mt][nt][r] + bi[nt];
            }
        }
}

// ---------------- fused: self-term + CSR gather + relu + BN + combine -------
// 16 lanes/node x 8 cols (ushort8): 4 nodes per wave; 2-way edge unroll ->
// up to 8 outstanding z-gathers per wave (MLP for the L3-latency-bound loop).
template<bool FIRST>
__global__ __launch_bounds__(256) void agg_kernel(
    const int* __restrict__ ptr, const int4* __restrict__ edata,
    const float* __restrict__ comb,
    const float* __restrict__ rdeg, const float* __restrict__ root,
    const float* __restrict__ gamma, const float* __restrict__ beta,
    const float* __restrict__ mean, const float* __restrict__ var,
    const unsigned short* __restrict__ zb, unsigned short* __restrict__ hb,
    float fi, int N)
{
    int n = blockIdx.x * 16 + (threadIdx.x >> 4);
    if (n >= N) return;
    int c = (threadIdx.x & 15) * 8;

    ushort8v zv = *reinterpret_cast<const ushort8v*>(zb + (long)n * HID + c);
    floatx4 rt0 = *reinterpret_cast<const floatx4*>(root + c);
    floatx4 rt1 = *reinterpret_cast<const floatx4*>(root + c + 4);
    float rd = rdeg[n];
    float acc[8];
#pragma unroll
    for (int j = 0; j < 4; ++j) {
        acc[j]     = fmaxf(bf2f(zv[j])     + rt0[j], 0.f) * rd;
        acc[j + 4] = fmaxf(bf2f(zv[j + 4]) + rt1[j], 0.f) * rd;
    }

    int jb = ptr[n], je = ptr[n + 1];
    int j2 = jb;
    for (; j2 + 1 < je; j2 += 2) {                   // paired: 2 gathers in flight
        int4 e0 = edata[j2];
        int4 e1 = edata[j2 + 1];
        ushort8v z0 = *reinterpret_cast<const ushort8v*>(zb + (long)e0.x * HID + c);
        ushort8v z1 = *reinterpret_cast<const ushort8v*>(zb + (long)e1.x * HID + c);
        floatx4 v00 = *reinterpret_cast<const floatx4*>(comb + e0.y * HID + c);
        floatx4 v01 = *reinterpret_cast<const floatx4*>(comb + e0.y * HID + c + 4);
        floatx4 v10 = *reinterpret_cast<const floatx4*>(comb + e1.y * HID + c);
        floatx4 v11 = *reinterpret_cast<const floatx4*>(comb + e1.y * HID + c + 4);
        float n0 = __builtin_bit_cast(float, e0.z);
        float n1 = __builtin_bit_cast(float, e1.z);
#pragma unroll
        for (int j = 0; j < 4; ++j) {
            acc[j]     += fmaxf(bf2f(z0[j])     + v00[j], 0.f) * n0;
            acc[j + 4] += fmaxf(bf2f(z0[j + 4]) + v01[j], 0.f) * n0;
            acc[j]     += fmaxf(bf2f(z1[j])     + v10[j], 0.f) * n1;
            acc[j + 4] += fmaxf(bf2f(z1[j + 4]) + v11[j], 0.f) * n1;
        }
    }
    if (j2 < je) {                                   // tail edge
        int4 e0 = edata[j2];
        ushort8v z0 = *reinterpret_cast<const ushort8v*>(zb + (long)e0.x * HID + c);
        floatx4 v00 = *reinterpret_cast<const floatx4*>(comb + e0.y * HID + c);
        floatx4 v01 = *reinterpret_cast<const floatx4*>(comb + e0.y * HID + c + 4);
        float n0 = __builtin_bit_cast(float, e0.z);
#pragma unroll
        for (int j = 0; j < 4; ++j) {
            acc[j]     += fmaxf(bf2f(z0[j])     + v00[j], 0.f) * n0;
            acc[j + 4] += fmaxf(bf2f(z0[j + 4]) + v01[j], 0.f) * n0;
        }
    }

    floatx4 gm0 = *reinterpret_cast<const floatx4*>(gamma + c);
    floatx4 gm1 = *reinterpret_cast<const floatx4*>(gamma + c + 4);
    floatx4 bt0 = *reinterpret_cast<const floatx4*>(beta + c);
    floatx4 bt1 = *reinterpret_cast<const floatx4*>(beta + c + 4);
    floatx4 mn0 = *reinterpret_cast<const floatx4*>(mean + c);
    floatx4 mn1 = *reinterpret_cast<const floatx4*>(mean + c + 4);
    floatx4 vr0 = *reinterpret_cast<const floatx4*>(var + c);
    floatx4 vr1 = *reinterpret_cast<const floatx4*>(var + c + 4);
    unsigned short* hp = hb + (long)n * HID + c;
    ushort8v hv;
    if constexpr (!FIRST) hv = *reinterpret_cast<const ushort8v*>(hp);
    ushort8v o;
#pragma unroll
    for (int j = 0; j < 4; ++j) {
        float t0 = fmaxf(acc[j], 0.f);
        float t1 = fmaxf(acc[j + 4], 0.f);
        t0 = (t0 - mn0[j]) * (gm0[j] * rsqrtf(vr0[j] + 1e-5f)) + bt0[j];
        t1 = (t1 - mn1[j]) * (gm1[j] * rsqrtf(vr1[j] + 1e-5f)) + bt1[j];
        float h0, h1;
        if constexpr (FIRST) { h0 = t0; h1 = t1; }   // fi = 0
        else {
            h0 = fi * bf2f(hv[j])     + (1.f - fi) * t0;
            h1 = fi * bf2f(hv[j + 4]) + (1.f - fi) * t1;
        }
        o[j]     = f2bf(h0);
        o[j + 4] = f2bf(h1);
    }
    *reinterpret_cast<ushort8v*>(hp) = o;
}

// ---------------- mean-pool per graph -> bf16 pooled[G][128] ----------------
__global__ __launch_bounds__(256) void pool_kernel(
    const unsigned short* __restrict__ hb, const int* __restrict__ gptr,
    unsigned short* __restrict__ pb, int G)
{
    int g = blockIdx.x;
    if (g >= G) return;
    int tid = threadIdx.x;
    int sub = tid >> 5;                // 8 node-lanes
    int c = (tid & 31) * 4;
    int lo = gptr[g], hi = gptr[g + 1];
    floatx4 s = {0.f, 0.f, 0.f, 0.f};
    for (int n = lo + sub; n < hi; n += 8) {
        ushort4v hv = *reinterpret_cast<const ushort4v*>(hb + (long)n * HID + c);
#pragma unroll
        for (int j = 0; j < 4; ++j) s[j] += bf2f(hv[j]);
    }
    __shared__ float ps[8][HID];
    *reinterpret_cast<floatx4*>(&ps[sub][c]) = s;
    __syncthreads();
    if (tid < HID) {
        float sum = 0.f;
#pragma unroll
        for (int k = 0; k < 8; ++k) sum += ps[k][tid];
        float cnt = (hi > lo) ? (float)(hi - lo) : 1.f;
        pb[(long)g * HID + tid] = f2bf(sum / cnt);
    }
}

extern "C" void kernel_launch(void* const* d_in, const int* in_sizes, int n_in,
                              void* d_out, int out_size, void* d_ws, size_t ws_size,
                              hipStream_t stream)
{
    const int* x          = (const int*)d_in[0];
    const int* ei         = (const int*)d_in[1];
    const int* attr       = (const int*)d_in[2];
    const int* batch      = (const int*)d_in[3];
    const float* atom_emb = (const float*)d_in[4];
    const float* bond_emb = (const float*)d_in[5];
    const float* conv_W   = (const float*)d_in[6];
    const float* conv_b   = (const float*)d_in[7];
    const float* root     = (const float*)d_in[8];
    const float* gamma    = (const float*)d_in[9];
    const float* beta     = (const float*)d_in[10];
    const float* mean     = (const float*)d_in[11];
    const float* var      = (const float*)d_in[12];
    const float* lin_W    = (const float*)d_in[13];
    const float* lin_b    = (const float*)d_in[14];
    float* out = (float*)d_out;

    const int N = in_sizes[0] / 9;
    const int E = in_sizes[1] / 2;
    const int G = out_size / HID;
    const int B = (N + 255) / 256;

    auto al = [](size_t b) { return (b + 255) & ~(size_t)255; };
    const size_t need =
        al((size_t)N * HID * 2) +     // hb
        al((size_t)N * HID * 2) +     // zb
        al((size_t)(N + 1) * 4) +     // ptr
        al((size_t)N * 4) +           // cursor
        al((size_t)E * 16) +          // edata
        al((size_t)N * 4) +           // indeg
        al((size_t)2048 * 4) * 2 +    // partial + offs
        al((size_t)N * 4) * 2 +       // rdeg + dis
        al((size_t)(G + 1) * 4) +     // gptr
        al((size_t)(G + 128) * HID * 2) + // pooled bf16 (+tail pad)
        al((size_t)60 * HID * 4) +    // comb
        al((size_t)HID * HID * 2) * 2; // Wb + linWb

    if (ws_size < need || B > 2048) {
        float v = (B > 2048) ? 3000.f : (1000.f + (float)(ws_size >> 20));
        long n = (long)out_size;
        diag_kernel<<<(int)((n + 255) / 256), 256, 0, stream>>>(out, n, v);
        return;
    }

    char* wsp = (char*)d_ws;
    size_t used = 0;
    auto alloc = [&](size_t bytes) { char* p = wsp + used; used += al(bytes); return p; };
    unsigned short* hb = (unsigned short*)alloc((size_t)N * HID * 2);
    unsigned short* zb = (unsigned short*)alloc((size_t)N * HID * 2);
    int* ptr     = (int*)alloc((size_t)(N + 1) * 4);
    int* cursor  = (int*)alloc((size_t)N * 4);
    int4* edata  = (int4*)alloc((size_t)E * 16);
    int* indeg   = (int*)alloc((size_t)N * 4);
    int* partial = (int*)alloc((size_t)2048 * 4);
    int* offs    = (int*)alloc((size_t)2048 * 4);
    float* rdeg  = (float*)alloc((size_t)N * 4);
    float* dis   = (float*)alloc((size_t)N * 4);
    int* gptr    = (int*)alloc((size_t)(G + 1) * 4);
    unsigned short* pb = (unsigned short*)alloc((size_t)(G + 128) * HID * 2);
    float* comb  = (float*)alloc((size_t)60 * HID * 4);
    unsigned short* Wb    = (unsigned short*)alloc((size_t)HID * HID * 2);
    unsigned short* linWb = (unsigned short*)alloc((size_t)HID * HID * 2);

    // ---- prologue ----
    fillrd_kernel<<<B, 256, 0, stream>>>(rdeg, indeg, N);
    cvtW_kernel<<<(HID * HID + 255) / 256, 256, 0, stream>>>(conv_W, Wb);
    cvtW_kernel<<<(HID * HID + 255) / 256, 256, 0, stream>>>(lin_W, linWb);
    combemb_kernel<<<60, 128, 0, stream>>>(bond_emb, comb);
    encode_kernel<<<(N + 7) / 8, 256, 0, stream>>>(x, atom_emb, hb, N);
    hist_kernel<<<1024, 256, 0, stream>>>(ei, rdeg, indeg, E);
    fdeg_kernel<<<B, 256, 0, stream>>>(rdeg, dis, N);
    bsum_kernel<<<B, 256, 0, stream>>>(indeg, partial, N);
    scan1_kernel<<<1, 256, 0, stream>>>(partial, offs, ptr, B, N);
    scan2_kernel<<<B, 256, 0, stream>>>(indeg, offs, ptr, cursor, N);
    fillcsr_kernel<<<1024, 256, 0, stream>>>(ei, attr, dis, cursor, edata, E);
    gptr_kernel<<<B, 256, 0, stream>>>(batch, gptr, N, G);

    // ---- loop (i=1 is identity: h = 1*old + 0*z, skipped) ----
    const float fis[4] = {0.f, 2.f, 3.f, 4.f};
    const int gemm_blocks = (N + 127) / 128;
    const int agg_blocks = (N + 15) / 16;
    for (int t = 0; t < 4; ++t) {
        gemm_kernel<<<gemm_blocks, 256, 0, stream>>>(hb, Wb, conv_b, zb, N);
        if (t == 0)
            agg_kernel<true ><<<agg_blocks, 256, 0, stream>>>(ptr, edata, comb, rdeg, root,
                                                              gamma, beta, mean, var,
                                                              zb, hb, fis[t], N);
        else
            agg_kernel<false><<<agg_blocks, 256, 0, stream>>>(ptr, edata, comb, rdeg, root,
                                                              gamma, beta, mean, var,
                                                              zb, hb, fis[t], N);
    }

    // ---- mean-pool (bf16) + MFMA final linear (fp32 out) ----
    pool_kernel<<<G, 256, 0, stream>>>(hb, gptr, pb, G);
    linmm_kernel<<<(G + 127) / 128, 256, 0, stream>>>(pb, linWb, lin_b, out, G);
}